// Round 10
// baseline (1063.210 us; speedup 1.0000x reference)
//
#include <hip/hip_runtime.h>

// EPD GNN, r21. r20 (620.6us best) + 512-thread blocks for k_genc/k_fused3:
// LDS 78.3KB x2 = 156.7KB <= 160KB and VGPR 128 x 16 waves = exact budget ->
// 16 waves/CU resident (2x r20) and each 64KB W-stage amortized over 16 tiles
// (halves W staging traffic, doubles cross-phase overlap). launch_bounds(512,4)
// pins VGPR<=128 (kernels already at 124-128). Bit-exact. Also bfuse merged
// into wfuse grid (-1 launch).

#define NN 50000
#define EE 400000
#define GG 8
#define NBLK 196   // ceil(NN/256)
#define BGRID 256  // 512-thread kernels: 2048 waves over 3125 tiles

typedef __attribute__((ext_vector_type(8))) short short8;
typedef __attribute__((ext_vector_type(4))) float floatx4;

__device__ __forceinline__ unsigned short f2bf(float x) {
    unsigned u = __float_as_uint(x);
    u += 0x7FFF + ((u >> 16) & 1);
    return (unsigned short)(u >> 16);
}
__device__ __forceinline__ float bf2f(unsigned short h) {
    return __uint_as_float(((unsigned)h) << 16);
}
__device__ __forceinline__ void cvt8(const float* v, short8& hi, short8& lo) {
#pragma unroll
    for (int j = 0; j < 8; ++j) {
        unsigned short h = f2bf(v[j]);
        hi[j] = (short)h;
        lo[j] = (short)f2bf(v[j] - bf2f(h));
    }
}

// ---------------- CSR build ----------------
__global__ void k_count(const int* __restrict__ ei, int* __restrict__ deg) {
    int i = blockIdx.x * 256 + threadIdx.x;
    if (i < EE) atomicAdd(&deg[ei[EE + i]], 1);
}

__global__ __launch_bounds__(256) void k_scan1(const int* __restrict__ deg, int* __restrict__ ex,
                                               int* __restrict__ blksum) {
    __shared__ int s[256];
    const int t = threadIdx.x;
    int i = blockIdx.x * 256 + t;
    int v = (i < NN) ? deg[i] : 0;
    s[t] = v;
    __syncthreads();
    for (int off = 1; off < 256; off <<= 1) {
        int x = (t >= off) ? s[t - off] : 0;
        __syncthreads();
        s[t] += x;
        __syncthreads();
    }
    if (i < NN) ex[i] = s[t] - v;
    if (t == 255) blksum[blockIdx.x] = s[255];
}

__global__ __launch_bounds__(256) void k_scan2(int* __restrict__ blksum) {
    __shared__ int s[256];
    const int t = threadIdx.x;
    int v = (t < NBLK) ? blksum[t] : 0;
    s[t] = v;
    __syncthreads();
    for (int off = 1; off < 256; off <<= 1) {
        int x = (t >= off) ? s[t - off] : 0;
        __syncthreads();
        s[t] += x;
        __syncthreads();
    }
    if (t < NBLK) blksum[t] = s[t] - v;
}

__global__ void k_scan3(const int* __restrict__ ex, const int* __restrict__ blkoff,
                        int* __restrict__ row_ptr, int* __restrict__ cursor) {
    int i = blockIdx.x * 256 + threadIdx.x;
    if (i < NN) {
        int v = ex[i] + blkoff[blockIdx.x];
        row_ptr[i] = v;
        cursor[i] = v;
    }
    if (i == 0) row_ptr[NN] = EE;
}

__global__ void k_scatter(const int* __restrict__ ei, const float* __restrict__ ea,
                          int* __restrict__ cursor, int* __restrict__ src_sorted,
                          float4* __restrict__ ea_s) {
    int e = blockIdx.x * 256 + threadIdx.x;
    if (e >= EE) return;
    int s = ei[e], d = ei[EE + e];
    int p = atomicAdd(&cursor[d], 1);
    src_sorted[p] = s;
    ea_s[p] = make_float4(ea[3 * e], ea[3 * e + 1], ea[3 * e + 2], 0.f);
}

// ---------------- per-graph counts (once): cnt_node, cnt_bc ----------------
__global__ __launch_bounds__(256) void k_counts(const int* __restrict__ batch, const float* __restrict__ xm,
                                                float* __restrict__ cnt_node, float* __restrict__ cnt_bc) {
    __shared__ float cn[8], cb[8];
    const int t = threadIdx.x;
    if (t < 8) { cn[t] = 0.f; cb[t] = 0.f; }
    __syncthreads();
    int i = blockIdx.x * 256 + t;
    if (i < NN) {
        int g = batch[i];
        atomicAdd(&cn[g], 1.f);
        atomicAdd(&cb[g], xm[3 * i + 2]);
    }
    __syncthreads();
    if (t < 8) {
        if (cn[t] != 0.f) atomicAdd(&cnt_node[t], cn[t]);
        if (cb[t] != 0.f) atomicAdd(&cnt_bc[t], cb[t]);
    }
}

// ---------------- weight fusion (block 64 = bfuse): Wf = Wm2 @ Wu1[128:256], bf = bu1 + bm2 @ Wu1[128:256] ----------------
__global__ __launch_bounds__(256) void k_wfuse(const float* __restrict__ Wm2, const float* __restrict__ Wu1,
                                               const float* __restrict__ bm2, const float* __restrict__ bu1,
                                               float* __restrict__ Wf, float* __restrict__ bf) {
    if (blockIdx.x == 64) {
        int c = threadIdx.x;
        if (c < 128) {
            float s = bu1[c];
            for (int k = 0; k < 128; ++k) s += bm2[k] * Wu1[(128 + k) * 128 + c];
            bf[c] = s;
        }
        return;
    }
    int idx = blockIdx.x * 256 + threadIdx.x;   // 16384
    int r = idx >> 7, c = idx & 127;
    float s = 0.f;
    for (int k = 0; k < 128; ++k) s += Wm2[r * 128 + k] * Wu1[(128 + k) * 128 + c];
    Wf[idx] = s;
}

// ---------------- weight packing ----------------
// normal (ids 0,3,4):  k = k0*32 + quad*8 + j
// permuted (ids 1,2,5,6): k = k0*32 + 16*(j>>2) + 4*quad + (j&3)
__global__ __launch_bounds__(256) void k_pack_all(
    const float* __restrict__ We2, const float* __restrict__ Wm1,
    const float* __restrict__ Wu1, const float* __restrict__ Wf,
    const float* __restrict__ Wu2, const float* __restrict__ Wd1,
    short* __restrict__ We2h, short* __restrict__ We2l,
    short* __restrict__ Wm1sh, short* __restrict__ Wm1sl,
    short* __restrict__ Wm1dh, short* __restrict__ Wm1dl,
    short* __restrict__ Wu1ah, short* __restrict__ Wu1al,
    short* __restrict__ Wfh, short* __restrict__ Wfl,
    short* __restrict__ Wu2h, short* __restrict__ Wu2l,
    short* __restrict__ Wd1h, short* __restrict__ Wd1l) {
    int b = blockIdx.x;
    int id = b >> 6;
    int p = (b & 63) * 256 + threadIdx.x;   // 0..16383
    const float* W;
    short *hi, *lo;
    switch (id) {
        case 0: W = We2; hi = We2h; lo = We2l; break;
        case 1: W = Wm1; hi = Wm1sh; lo = Wm1sl; break;
        case 2: W = Wm1 + 16384; hi = Wm1dh; lo = Wm1dl; break;
        case 3: W = Wu1; hi = Wu1ah; lo = Wu1al; break;
        case 4: W = Wf; hi = Wfh; lo = Wfl; break;
        case 5: W = Wu2; hi = Wu2h; lo = Wu2l; break;
        default: W = Wd1; hi = Wd1h; lo = Wd1l; break;
    }
    int j = p & 7;
    int lane = (p >> 3) & 63;
    int chunk = p >> 9;          // 0..31
    int k0 = chunk & 3, nt = chunk >> 2;
    int quad = lane >> 4;
    int n = nt * 16 + (lane & 15);
    bool perm = (id == 1) || (id == 2) || (id == 5) || (id == 6);
    int k;
    if (perm) k = k0 * 32 + ((j >> 2) << 4) + (quad << 2) + (j & 3);
    else k = k0 * 32 + quad * 8 + j;
    float w = W[k * 128 + n];
    unsigned short h = f2bf(w);
    hi[p] = (short)h;
    lo[p] = (short)f2bf(w - bf2f(h));
}

// ---------------- fused encoder (512 threads): h, Ps, Pd (+ partial stats) ----------------
__global__ __launch_bounds__(512, 4) void k_genc(
    const float* __restrict__ x, const float* __restrict__ xm,
    const float* __restrict__ We1, const float* __restrict__ be1,
    const short* __restrict__ W2h, const short* __restrict__ W2l,
    const float* __restrict__ be2,
    const short* __restrict__ Wsh, const short* __restrict__ Wsl,
    const short* __restrict__ Wdh, const short* __restrict__ Wdl,
    const float* __restrict__ bm1, const int* __restrict__ batch,
    float* __restrict__ hout, float* __restrict__ Ps, float* __restrict__ Pd,
    float* __restrict__ part_h, float* __restrict__ part_hbc) {
    __shared__ __align__(16) short sWh[16384];
    __shared__ __align__(16) short sWl[16384];
    __shared__ __align__(16) float swe[1024];   // native We1 layout [kk][c]
    __shared__ float sbe[128];
    __shared__ float ldsH[1024];
    __shared__ float ldsB[1024];
    const int tid = threadIdx.x;
    const int wave = tid >> 6, lane = tid & 63;
    const int m16 = lane & 15, quad = lane >> 4;
    const int t0 = blockIdx.x * 8 + wave;      // 0..2047
    const int t1 = t0 + BGRID * 8;             // 2048..4095
    const bool h1 = (t1 < 3125);
    const int r0 = t0 * 16 + m16;
    const int r1 = (h1 ? t1 * 16 : 0) + m16;

    auto copyW = [&](const short* gh, const short* gl) {
        const float4* sH = (const float4*)gh;
        const float4* sL = (const float4*)gl;
        float4* dH = (float4*)sWh;
        float4* dL = (float4*)sWl;
#pragma unroll
        for (int u = 0; u < 4; ++u) {
            int i = tid + u * 512;
            dH[i] = sH[i];
            dL[i] = sL[i];
        }
    };

    {
        copyW(W2h, W2l);
        for (int i = tid; i < 1024; i += 512) {
            swe[i] = We1[i];
            ldsH[i] = 0.f;
            ldsB[i] = 0.f;
        }
        if (tid < 128) sbe[tid] = be1[tid];
    }
    float in0[8], in1[8];
#pragma unroll
    for (int k = 0; k < 5; ++k) { in0[k] = x[r0 * 5 + k]; in1[k] = x[r1 * 5 + k]; }
#pragma unroll
    for (int k = 0; k < 3; ++k) { in0[5 + k] = xm[r0 * 3 + k]; in1[5 + k] = xm[r1 * 3 + k]; }
    int g0 = batch[r0], g1 = batch[r1];
    __syncthreads();
    // enc1 outputs in A-fragment slot order: c = k0*32 + quad*8 + j
    short8 ah0[4], al0[4], ah1[4], al1[4];
#pragma unroll
    for (int k0 = 0; k0 < 4; ++k0) {
        float tv[8];
#pragma unroll
        for (int j = 0; j < 8; ++j) {
            int c = k0 * 32 + quad * 8 + j;
            float s = sbe[c];
#pragma unroll
            for (int kk = 0; kk < 8; ++kk) s += in0[kk] * swe[kk * 128 + c];
            tv[j] = fmaxf(s, 0.f);
        }
        cvt8(tv, ah0[k0], al0[k0]);
    }
#pragma unroll
    for (int k0 = 0; k0 < 4; ++k0) {
        float tv[8];
#pragma unroll
        for (int j = 0; j < 8; ++j) {
            int c = k0 * 32 + quad * 8 + j;
            float s = sbe[c];
#pragma unroll
            for (int kk = 0; kk < 8; ++kk) s += in1[kk] * swe[kk * 128 + c];
            tv[j] = fmaxf(s, 0.f);
        }
        cvt8(tv, ah1[k0], al1[k0]);
    }
    const int fb = lane << 3;
    floatx4 acc0[8], acc1[8];
    auto mmacc = [&](const short8 xh0[4], const short8 xl0[4],
                     const short8 xh1[4], const short8 xl1[4]) {
#pragma unroll
        for (int k0 = 0; k0 < 4; ++k0) {
#pragma unroll
            for (int nt = 0; nt < 8; ++nt) {
                const int base = (((nt << 2) | k0) << 9) + fb;
                short8 bh = *(const short8*)&sWh[base];
                short8 bl = *(const short8*)&sWl[base];
                acc0[nt] = __builtin_amdgcn_mfma_f32_16x16x32_bf16(bh, xh0[k0], acc0[nt], 0, 0, 0);
                acc0[nt] = __builtin_amdgcn_mfma_f32_16x16x32_bf16(bl, xh0[k0], acc0[nt], 0, 0, 0);
                acc0[nt] = __builtin_amdgcn_mfma_f32_16x16x32_bf16(bh, xl0[k0], acc0[nt], 0, 0, 0);
                if (h1) {
                    acc1[nt] = __builtin_amdgcn_mfma_f32_16x16x32_bf16(bh, xh1[k0], acc1[nt], 0, 0, 0);
                    acc1[nt] = __builtin_amdgcn_mfma_f32_16x16x32_bf16(bl, xh1[k0], acc1[nt], 0, 0, 0);
                    acc1[nt] = __builtin_amdgcn_mfma_f32_16x16x32_bf16(bh, xl1[k0], acc1[nt], 0, 0, 0);
                }
            }
        }
    };

    // h = enc1@We2 + be2 (seeded)
#pragma unroll
    for (int nt = 0; nt < 8; ++nt) {
        float4 bv = *(const float4*)(be2 + nt * 16 + quad * 4);
        acc0[nt][0] = bv.x; acc0[nt][1] = bv.y; acc0[nt][2] = bv.z; acc0[nt][3] = bv.w;
        acc1[nt][0] = bv.x; acc1[nt][1] = bv.y; acc1[nt][2] = bv.z; acc1[nt][3] = bv.w;
    }
    mmacc(ah0, al0, ah1, al1);
    {
        float* d0 = hout + (size_t)r0 * 128 + quad * 4;
#pragma unroll
        for (int nt = 0; nt < 8; ++nt)
            *(float4*)(d0 + nt * 16) = make_float4(acc0[nt][0], acc0[nt][1], acc0[nt][2], acc0[nt][3]);
    }
    if (h1) {
        float* d1 = hout + (size_t)r1 * 128 + quad * 4;
#pragma unroll
        for (int nt = 0; nt < 8; ++nt)
            *(float4*)(d1 + nt * 16) = make_float4(acc1[nt][0], acc1[nt][1], acc1[nt][2], acc1[nt][3]);
    }
    // stats -> LDS accumulators
    {
        float bc = in0[7];
        int glo = __shfl(g0, 0), ghi = __shfl(g0, 15);
        if (glo == ghi) {
#pragma unroll
            for (int nt = 0; nt < 8; ++nt) {
                float4 v = make_float4(acc0[nt][0], acc0[nt][1], acc0[nt][2], acc0[nt][3]);
                float4 w = make_float4(v.x * bc, v.y * bc, v.z * bc, v.w * bc);
#pragma unroll
                for (int off = 1; off < 16; off <<= 1) {
                    v.x += __shfl_xor(v.x, off); v.y += __shfl_xor(v.y, off);
                    v.z += __shfl_xor(v.z, off); v.w += __shfl_xor(v.w, off);
                    w.x += __shfl_xor(w.x, off); w.y += __shfl_xor(w.y, off);
                    w.z += __shfl_xor(w.z, off); w.w += __shfl_xor(w.w, off);
                }
                if (m16 == 0) {
                    float* sp = &ldsH[glo * 128 + nt * 16 + quad * 4];
                    atomicAdd(sp + 0, v.x); atomicAdd(sp + 1, v.y);
                    atomicAdd(sp + 2, v.z); atomicAdd(sp + 3, v.w);
                    float* sq = &ldsB[glo * 128 + nt * 16 + quad * 4];
                    atomicAdd(sq + 0, w.x); atomicAdd(sq + 1, w.y);
                    atomicAdd(sq + 2, w.z); atomicAdd(sq + 3, w.w);
                }
            }
        } else {
#pragma unroll
            for (int nt = 0; nt < 8; ++nt)
#pragma unroll
                for (int i = 0; i < 4; ++i) {
                    atomicAdd(&ldsH[g0 * 128 + nt * 16 + quad * 4 + i], acc0[nt][i]);
                    atomicAdd(&ldsB[g0 * 128 + nt * 16 + quad * 4 + i], acc0[nt][i] * bc);
                }
        }
    }
    if (h1) {
        float bc = in1[7];
        int glo = __shfl(g1, 0), ghi = __shfl(g1, 15);
        if (glo == ghi) {
#pragma unroll
            for (int nt = 0; nt < 8; ++nt) {
                float4 v = make_float4(acc1[nt][0], acc1[nt][1], acc1[nt][2], acc1[nt][3]);
                float4 w = make_float4(v.x * bc, v.y * bc, v.z * bc, v.w * bc);
#pragma unroll
                for (int off = 1; off < 16; off <<= 1) {
                    v.x += __shfl_xor(v.x, off); v.y += __shfl_xor(v.y, off);
                    v.z += __shfl_xor(v.z, off); v.w += __shfl_xor(v.w, off);
                    w.x += __shfl_xor(w.x, off); w.y += __shfl_xor(w.y, off);
                    w.z += __shfl_xor(w.z, off); w.w += __shfl_xor(w.w, off);
                }
                if (m16 == 0) {
                    float* sp = &ldsH[glo * 128 + nt * 16 + quad * 4];
                    atomicAdd(sp + 0, v.x); atomicAdd(sp + 1, v.y);
                    atomicAdd(sp + 2, v.z); atomicAdd(sp + 3, v.w);
                    float* sq = &ldsB[glo * 128 + nt * 16 + quad * 4];
                    atomicAdd(sq + 0, w.x); atomicAdd(sq + 1, w.y);
                    atomicAdd(sq + 2, w.z); atomicAdd(sq + 3, w.w);
                }
            }
        } else {
#pragma unroll
            for (int nt = 0; nt < 8; ++nt)
#pragma unroll
                for (int i = 0; i < 4; ++i) {
                    atomicAdd(&ldsH[g1 * 128 + nt * 16 + quad * 4 + i], acc1[nt][i]);
                    atomicAdd(&ldsB[g1 * 128 + nt * 16 + quad * 4 + i], acc1[nt][i] * bc);
                }
        }
    }
    // convert in-register h -> permuted A-fragments
    short8 ph0[4], pl0[4], ph1[4], pl1[4];
#pragma unroll
    for (int k0 = 0; k0 < 4; ++k0) {
        float v[8] = {acc0[2 * k0][0], acc0[2 * k0][1], acc0[2 * k0][2], acc0[2 * k0][3],
                      acc0[2 * k0 + 1][0], acc0[2 * k0 + 1][1], acc0[2 * k0 + 1][2], acc0[2 * k0 + 1][3]};
        cvt8(v, ph0[k0], pl0[k0]);
    }
#pragma unroll
    for (int k0 = 0; k0 < 4; ++k0) {
        float v[8] = {acc1[2 * k0][0], acc1[2 * k0][1], acc1[2 * k0][2], acc1[2 * k0][3],
                      acc1[2 * k0 + 1][0], acc1[2 * k0 + 1][1], acc1[2 * k0 + 1][2], acc1[2 * k0 + 1][3]};
        cvt8(v, ph1[k0], pl1[k0]);
    }
    __syncthreads();
    // dense per-block partial store (after sync: all LDS atomics landed)
    {
        float* ph = part_h + (size_t)blockIdx.x * 1024;
        float* pb = part_hbc + (size_t)blockIdx.x * 1024;
        for (int i = tid; i < 1024; i += 512) { ph[i] = ldsH[i]; pb[i] = ldsB[i]; }
    }
    // Ps = h@Wm1sp
    copyW(Wsh, Wsl);
    __syncthreads();
#pragma unroll
    for (int nt = 0; nt < 8; ++nt) { acc0[nt] = (floatx4)0.f; acc1[nt] = (floatx4)0.f; }
    mmacc(ph0, pl0, ph1, pl1);
    {
        float* d0 = Ps + (size_t)r0 * 128 + quad * 4;
#pragma unroll
        for (int nt = 0; nt < 8; ++nt)
            *(float4*)(d0 + nt * 16) = make_float4(acc0[nt][0], acc0[nt][1], acc0[nt][2], acc0[nt][3]);
        if (h1) {
            float* d1 = Ps + (size_t)r1 * 128 + quad * 4;
#pragma unroll
            for (int nt = 0; nt < 8; ++nt)
                *(float4*)(d1 + nt * 16) = make_float4(acc1[nt][0], acc1[nt][1], acc1[nt][2], acc1[nt][3]);
        }
    }
    // Pd = h@Wm1dp + bm1 (seeded)
    __syncthreads();
    copyW(Wdh, Wdl);
    __syncthreads();
#pragma unroll
    for (int nt = 0; nt < 8; ++nt) {
        float4 bv = *(const float4*)(bm1 + nt * 16 + quad * 4);
        acc0[nt][0] = bv.x; acc0[nt][1] = bv.y; acc0[nt][2] = bv.z; acc0[nt][3] = bv.w;
        acc1[nt][0] = bv.x; acc1[nt][1] = bv.y; acc1[nt][2] = bv.z; acc1[nt][3] = bv.w;
    }
    mmacc(ph0, pl0, ph1, pl1);
    {
        float* d0 = Pd + (size_t)r0 * 128 + quad * 4;
#pragma unroll
        for (int nt = 0; nt < 8; ++nt)
            *(float4*)(d0 + nt * 16) = make_float4(acc0[nt][0], acc0[nt][1], acc0[nt][2], acc0[nt][3]);
        if (h1) {
            float* d1 = Pd + (size_t)r1 * 128 + quad * 4;
#pragma unroll
            for (int nt = 0; nt < 8; ++nt)
                *(float4*)(d1 + nt * 16) = make_float4(acc1[nt][0], acc1[nt][1], acc1[nt][2], acc1[nt][3]);
        }
    }
}

// ---------------- FUSED3 (512 threads, 2-tile): tmp=h@Wu1a+gt+bf ; pre=relu(tmp+accm@Wf) ; h'=h+pre@Wu2p ;
// MODE 0 (EMIT): store h', stats->partf, Ps=h'@Wm1sp, Pd=h'@Wm1dp+bm1
// MODE 1 (DEC):  out = relu(h'@Wd1p + bd1) @ Wd2 + bd2   (h' never stored)
template <int MODE>
__global__ __launch_bounds__(512, 4) void k_fused3(
    const float* __restrict__ hbuf, const float* __restrict__ accm,
    const short* __restrict__ W1h, const short* __restrict__ W1l,
    const short* __restrict__ W2h, const short* __restrict__ W2l,
    const short* __restrict__ W3h, const short* __restrict__ W3l,
    const short* __restrict__ Wsh, const short* __restrict__ Wsl,
    const short* __restrict__ Wdh, const short* __restrict__ Wdl,
    const float* __restrict__ gt, const float* __restrict__ bf3,
    const float* __restrict__ bu2, const float* __restrict__ bm1,
    const float* __restrict__ bd1, const float* __restrict__ Wd2,
    const float* __restrict__ bd2, const int* __restrict__ batch,
    float* __restrict__ hout, float* __restrict__ Ps, float* __restrict__ Pd,
    float* __restrict__ partf, float* __restrict__ outp) {
    __shared__ __align__(16) short sWh[16384];
    __shared__ __align__(16) short sWl[16384];
    __shared__ float ldsH[1024];
    const int tid = threadIdx.x;
    const int wave = tid >> 6, lane = tid & 63;
    const int m16 = lane & 15, quad = lane >> 4;
    const int t0 = blockIdx.x * 8 + wave;
    const int t1 = t0 + BGRID * 8;
    const bool h1 = (t1 < 3125);
    const int r0 = t0 * 16 + m16;
    const int r1 = (h1 ? t1 * 16 : 0) + m16;

    auto copyW = [&](const short* gh, const short* gl) {
        const float4* sH = (const float4*)gh;
        const float4* sL = (const float4*)gl;
        float4* dH = (float4*)sWh;
        float4* dL = (float4*)sWl;
#pragma unroll
        for (int u = 0; u < 4; ++u) {
            int i = tid + u * 512;
            dH[i] = sH[i];
            dL[i] = sL[i];
        }
    };

    const float* Ap0 = hbuf + (size_t)r0 * 128 + quad * 8;
    const float* Ap1 = hbuf + (size_t)r1 * 128 + quad * 8;
    float4 a0[8], a1[8];
#pragma unroll
    for (int k0 = 0; k0 < 4; ++k0) {
        a0[k0 * 2 + 0] = *(const float4*)(Ap0 + k0 * 32);
        a0[k0 * 2 + 1] = *(const float4*)(Ap0 + k0 * 32 + 4);
        a1[k0 * 2 + 0] = *(const float4*)(Ap1 + k0 * 32);
        a1[k0 * 2 + 1] = *(const float4*)(Ap1 + k0 * 32 + 4);
    }
    int g0 = batch[r0], g1 = batch[r1];
    if (MODE == 0) {
        for (int i = tid; i < 1024; i += 512) ldsH[i] = 0.f;
    }
    copyW(W1h, W1l);
    __syncthreads();

    short8 hh0[4], hl0[4], hh1[4], hl1[4];
#pragma unroll
    for (int k0 = 0; k0 < 4; ++k0) {
        float v[8] = {a0[k0 * 2].x, a0[k0 * 2].y, a0[k0 * 2].z, a0[k0 * 2].w,
                      a0[k0 * 2 + 1].x, a0[k0 * 2 + 1].y, a0[k0 * 2 + 1].z, a0[k0 * 2 + 1].w};
        cvt8(v, hh0[k0], hl0[k0]);
    }
#pragma unroll
    for (int k0 = 0; k0 < 4; ++k0) {
        float v[8] = {a1[k0 * 2].x, a1[k0 * 2].y, a1[k0 * 2].z, a1[k0 * 2].w,
                      a1[k0 * 2 + 1].x, a1[k0 * 2 + 1].y, a1[k0 * 2 + 1].z, a1[k0 * 2 + 1].w};
        cvt8(v, hh1[k0], hl1[k0]);
    }

    const int fb = lane << 3;
    floatx4 acc0[8], acc1[8];
    auto mmacc = [&](const short8 xh0[4], const short8 xl0[4],
                     const short8 xh1[4], const short8 xl1[4]) {
#pragma unroll
        for (int k0 = 0; k0 < 4; ++k0) {
#pragma unroll
            for (int nt = 0; nt < 8; ++nt) {
                const int base = (((nt << 2) | k0) << 9) + fb;
                short8 bh = *(const short8*)&sWh[base];
                short8 bl = *(const short8*)&sWl[base];
                acc0[nt] = __builtin_amdgcn_mfma_f32_16x16x32_bf16(bh, xh0[k0], acc0[nt], 0, 0, 0);
                acc0[nt] = __builtin_amdgcn_mfma_f32_16x16x32_bf16(bl, xh0[k0], acc0[nt], 0, 0, 0);
                acc0[nt] = __builtin_amdgcn_mfma_f32_16x16x32_bf16(bh, xl0[k0], acc0[nt], 0, 0, 0);
                if (h1) {
                    acc1[nt] = __builtin_amdgcn_mfma_f32_16x16x32_bf16(bh, xh1[k0], acc1[nt], 0, 0, 0);
                    acc1[nt] = __builtin_amdgcn_mfma_f32_16x16x32_bf16(bl, xh1[k0], acc1[nt], 0, 0, 0);
                    acc1[nt] = __builtin_amdgcn_mfma_f32_16x16x32_bf16(bh, xl1[k0], acc1[nt], 0, 0, 0);
                }
            }
        }
    };

    // gemm1: acc = bf + gt[g] + h@Wu1a  -> tmp
    {
        const float* gp0 = gt + g0 * 128 + quad * 4;
        const float* gp1 = gt + g1 * 128 + quad * 4;
#pragma unroll
        for (int nt = 0; nt < 8; ++nt) {
            float4 bv = *(const float4*)(bf3 + nt * 16 + quad * 4);
            float4 gv0 = *(const float4*)(gp0 + nt * 16);
            float4 gv1 = *(const float4*)(gp1 + nt * 16);
            acc0[nt][0] = bv.x + gv0.x; acc0[nt][1] = bv.y + gv0.y;
            acc0[nt][2] = bv.z + gv0.z; acc0[nt][3] = bv.w + gv0.w;
            acc1[nt][0] = bv.x + gv1.x; acc1[nt][1] = bv.y + gv1.y;
            acc1[nt][2] = bv.z + gv1.z; acc1[nt][3] = bv.w + gv1.w;
        }
    }
    mmacc(hh0, hl0, hh1, hl1);

    // accm loads (latency hides under W2 stage + sync)
    const float* Cp0 = accm + (size_t)r0 * 128 + quad * 8;
    const float* Cp1 = accm + (size_t)r1 * 128 + quad * 8;
    float4 c0[8], c1[8];
#pragma unroll
    for (int k0 = 0; k0 < 4; ++k0) {
        c0[k0 * 2 + 0] = *(const float4*)(Cp0 + k0 * 32);
        c0[k0 * 2 + 1] = *(const float4*)(Cp0 + k0 * 32 + 4);
        c1[k0 * 2 + 0] = *(const float4*)(Cp1 + k0 * 32);
        c1[k0 * 2 + 1] = *(const float4*)(Cp1 + k0 * 32 + 4);
    }
    __syncthreads();
    copyW(W2h, W2l);
    __syncthreads();

    short8 ch0[4], cl0[4], ch1[4], cl1[4];
#pragma unroll
    for (int k0 = 0; k0 < 4; ++k0) {
        float v[8] = {c0[k0 * 2].x, c0[k0 * 2].y, c0[k0 * 2].z, c0[k0 * 2].w,
                      c0[k0 * 2 + 1].x, c0[k0 * 2 + 1].y, c0[k0 * 2 + 1].z, c0[k0 * 2 + 1].w};
        cvt8(v, ch0[k0], cl0[k0]);
    }
#pragma unroll
    for (int k0 = 0; k0 < 4; ++k0) {
        float v[8] = {c1[k0 * 2].x, c1[k0 * 2].y, c1[k0 * 2].z, c1[k0 * 2].w,
                      c1[k0 * 2 + 1].x, c1[k0 * 2 + 1].y, c1[k0 * 2 + 1].z, c1[k0 * 2 + 1].w};
        cvt8(v, ch1[k0], cl1[k0]);
    }
    // gemm2: acc += accm@Wf -> pre = relu(acc)
    mmacc(ch0, cl0, ch1, cl1);

    short8 ph0[4], pl0[4], ph1[4], pl1[4];
#pragma unroll
    for (int k0 = 0; k0 < 4; ++k0) {
        float v[8] = {fmaxf(acc0[2 * k0][0], 0.f), fmaxf(acc0[2 * k0][1], 0.f),
                      fmaxf(acc0[2 * k0][2], 0.f), fmaxf(acc0[2 * k0][3], 0.f),
                      fmaxf(acc0[2 * k0 + 1][0], 0.f), fmaxf(acc0[2 * k0 + 1][1], 0.f),
                      fmaxf(acc0[2 * k0 + 1][2], 0.f), fmaxf(acc0[2 * k0 + 1][3], 0.f)};
        cvt8(v, ph0[k0], pl0[k0]);
    }
#pragma unroll
    for (int k0 = 0; k0 < 4; ++k0) {
        float v[8] = {fmaxf(acc1[2 * k0][0], 0.f), fmaxf(acc1[2 * k0][1], 0.f),
                      fmaxf(acc1[2 * k0][2], 0.f), fmaxf(acc1[2 * k0][3], 0.f),
                      fmaxf(acc1[2 * k0 + 1][0], 0.f), fmaxf(acc1[2 * k0 + 1][1], 0.f),
                      fmaxf(acc1[2 * k0 + 1][2], 0.f), fmaxf(acc1[2 * k0 + 1][3], 0.f)};
        cvt8(v, ph1[k0], pl1[k0]);
    }

    // re-seed acc = h + bu2 (epilogue layout, memory re-read)
    {
        const float* Ep0 = hbuf + (size_t)r0 * 128 + quad * 4;
        const float* Ep1 = hbuf + (size_t)r1 * 128 + quad * 4;
#pragma unroll
        for (int nt = 0; nt < 8; ++nt) {
            float4 bv = *(const float4*)(bu2 + nt * 16 + quad * 4);
            float4 e0 = *(const float4*)(Ep0 + nt * 16);
            float4 e1 = *(const float4*)(Ep1 + nt * 16);
            acc0[nt][0] = e0.x + bv.x; acc0[nt][1] = e0.y + bv.y;
            acc0[nt][2] = e0.z + bv.z; acc0[nt][3] = e0.w + bv.w;
            acc1[nt][0] = e1.x + bv.x; acc1[nt][1] = e1.y + bv.y;
            acc1[nt][2] = e1.z + bv.z; acc1[nt][3] = e1.w + bv.w;
        }
    }
    __syncthreads();
    copyW(W3h, W3l);
    __syncthreads();
    // gemm3: acc += pre@Wu2p -> h'
    mmacc(ph0, pl0, ph1, pl1);

    if (MODE == 0) {
        // store h'
        {
            float* d0 = hout + (size_t)r0 * 128 + quad * 4;
#pragma unroll
            for (int nt = 0; nt < 8; ++nt)
                *(float4*)(d0 + nt * 16) = make_float4(acc0[nt][0], acc0[nt][1], acc0[nt][2], acc0[nt][3]);
        }
        if (h1) {
            float* d1 = hout + (size_t)r1 * 128 + quad * 4;
#pragma unroll
            for (int nt = 0; nt < 8; ++nt)
                *(float4*)(d1 + nt * 16) = make_float4(acc1[nt][0], acc1[nt][1], acc1[nt][2], acc1[nt][3]);
        }
        // stats
        {
            int glo = __shfl(g0, 0), ghi = __shfl(g0, 15);
            if (glo == ghi) {
#pragma unroll
                for (int nt = 0; nt < 8; ++nt) {
                    float4 v = make_float4(acc0[nt][0], acc0[nt][1], acc0[nt][2], acc0[nt][3]);
#pragma unroll
                    for (int off = 1; off < 16; off <<= 1) {
                        v.x += __shfl_xor(v.x, off);
                        v.y += __shfl_xor(v.y, off);
                        v.z += __shfl_xor(v.z, off);
                        v.w += __shfl_xor(v.w, off);
                    }
                    if (m16 == 0) {
                        float* sp = &ldsH[glo * 128 + nt * 16 + quad * 4];
                        atomicAdd(sp + 0, v.x); atomicAdd(sp + 1, v.y);
                        atomicAdd(sp + 2, v.z); atomicAdd(sp + 3, v.w);
                    }
                }
            } else {
#pragma unroll
                for (int nt = 0; nt < 8; ++nt)
#pragma unroll
                    for (int i = 0; i < 4; ++i)
                        atomicAdd(&ldsH[g0 * 128 + nt * 16 + quad * 4 + i], acc0[nt][i]);
            }
        }
        if (h1) {
            int glo = __shfl(g1, 0), ghi = __shfl(g1, 15);
            if (glo == ghi) {
#pragma unroll
                for (int nt = 0; nt < 8; ++nt) {
                    float4 v = make_float4(acc1[nt][0], acc1[nt][1], acc1[nt][2], acc1[nt][3]);
#pragma unroll
                    for (int off = 1; off < 16; off <<= 1) {
                        v.x += __shfl_xor(v.x, off);
                        v.y += __shfl_xor(v.y, off);
                        v.z += __shfl_xor(v.z, off);
                        v.w += __shfl_xor(v.w, off);
                    }
                    if (m16 == 0) {
                        float* sp = &ldsH[glo * 128 + nt * 16 + quad * 4];
                        atomicAdd(sp + 0, v.x); atomicAdd(sp + 1, v.y);
                        atomicAdd(sp + 2, v.z); atomicAdd(sp + 3, v.w);
                    }
                }
            } else {
#pragma unroll
                for (int nt = 0; nt < 8; ++nt)
#pragma unroll
                    for (int i = 0; i < 4; ++i)
                        atomicAdd(&ldsH[g1 * 128 + nt * 16 + quad * 4 + i], acc1[nt][i]);
            }
        }
        // convert h' -> permuted fragments (reuse ph/pl)
#pragma unroll
        for (int k0 = 0; k0 < 4; ++k0) {
            float v[8] = {acc0[2 * k0][0], acc0[2 * k0][1], acc0[2 * k0][2], acc0[2 * k0][3],
                          acc0[2 * k0 + 1][0], acc0[2 * k0 + 1][1], acc0[2 * k0 + 1][2], acc0[2 * k0 + 1][3]};
            cvt8(v, ph0[k0], pl0[k0]);
        }
#pragma unroll
        for (int k0 = 0; k0 < 4; ++k0) {
            float v[8] = {acc1[2 * k0][0], acc1[2 * k0][1], acc1[2 * k0][2], acc1[2 * k0][3],
                          acc1[2 * k0 + 1][0], acc1[2 * k0 + 1][1], acc1[2 * k0 + 1][2], acc1[2 * k0 + 1][3]};
            cvt8(v, ph1[k0], pl1[k0]);
        }
        __syncthreads();
        {
            float* pf = partf + (size_t)blockIdx.x * 1024;
            for (int i = tid; i < 1024; i += 512) pf[i] = ldsH[i];
        }
        // Ps = h'@Wm1sp
        copyW(Wsh, Wsl);
        __syncthreads();
#pragma unroll
        for (int nt = 0; nt < 8; ++nt) { acc0[nt] = (floatx4)0.f; acc1[nt] = (floatx4)0.f; }
        mmacc(ph0, pl0, ph1, pl1);
        {
            float* d0 = Ps + (size_t)r0 * 128 + quad * 4;
#pragma unroll
            for (int nt = 0; nt < 8; ++nt)
                *(float4*)(d0 + nt * 16) = make_float4(acc0[nt][0], acc0[nt][1], acc0[nt][2], acc0[nt][3]);
            if (h1) {
                float* d1 = Ps + (size_t)r1 * 128 + quad * 4;
#pragma unroll
                for (int nt = 0; nt < 8; ++nt)
                    *(float4*)(d1 + nt * 16) = make_float4(acc1[nt][0], acc1[nt][1], acc1[nt][2], acc1[nt][3]);
            }
        }
        // Pd = h'@Wm1dp + bm1
        __syncthreads();
        copyW(Wdh, Wdl);
        __syncthreads();
#pragma unroll
        for (int nt = 0; nt < 8; ++nt) {
            float4 bv = *(const float4*)(bm1 + nt * 16 + quad * 4);
            acc0[nt][0] = bv.x; acc0[nt][1] = bv.y; acc0[nt][2] = bv.z; acc0[nt][3] = bv.w;
            acc1[nt][0] = bv.x; acc1[nt][1] = bv.y; acc1[nt][2] = bv.z; acc1[nt][3] = bv.w;
        }
        mmacc(ph0, pl0, ph1, pl1);
        {
            float* d0 = Pd + (size_t)r0 * 128 + quad * 4;
#pragma unroll
            for (int nt = 0; nt < 8; ++nt)
                *(float4*)(d0 + nt * 16) = make_float4(acc0[nt][0], acc0[nt][1], acc0[nt][2], acc0[nt][3]);
            if (h1) {
                float* d1 = Pd + (size_t)r1 * 128 + quad * 4;
#pragma unroll
                for (int nt = 0; nt < 8; ++nt)
                    *(float4*)(d1 + nt * 16) = make_float4(acc1[nt][0], acc1[nt][1], acc1[nt][2], acc1[nt][3]);
            }
        }
    } else {
        // DEC: convert h' -> permuted fragments, dec1 via Wd1p, dec2 in-register
#pragma unroll
        for (int k0 = 0; k0 < 4; ++k0) {
            float v[8] = {acc0[2 * k0][0], acc0[2 * k0][1], acc0[2 * k0][2], acc0[2 * k0][3],
                          acc0[2 * k0 + 1][0], acc0[2 * k0 + 1][1], acc0[2 * k0 + 1][2], acc0[2 * k0 + 1][3]};
            cvt8(v, ph0[k0], pl0[k0]);
        }
#pragma unroll
        for (int k0 = 0; k0 < 4; ++k0) {
            float v[8] = {acc1[2 * k0][0], acc1[2 * k0][1], acc1[2 * k0][2], acc1[2 * k0][3],
                          acc1[2 * k0 + 1][0], acc1[2 * k0 + 1][1], acc1[2 * k0 + 1][2], acc1[2 * k0 + 1][3]};
            cvt8(v, ph1[k0], pl1[k0]);
        }
        __syncthreads();
        copyW(Wdh, Wdl);   // Wd1 permuted pack
        __syncthreads();
#pragma unroll
        for (int nt = 0; nt < 8; ++nt) {
            float4 bv = *(const float4*)(bd1 + nt * 16 + quad * 4);
            acc0[nt][0] = bv.x; acc0[nt][1] = bv.y; acc0[nt][2] = bv.z; acc0[nt][3] = bv.w;
            acc1[nt][0] = bv.x; acc1[nt][1] = bv.y; acc1[nt][2] = bv.z; acc1[nt][3] = bv.w;
        }
        mmacc(ph0, pl0, ph1, pl1);
        float p00 = 0.f, p01 = 0.f, p02 = 0.f, p10 = 0.f, p11 = 0.f, p12 = 0.f;
#pragma unroll
        for (int nt = 0; nt < 8; ++nt) {
#pragma unroll
            for (int i = 0; i < 4; ++i) {
                int c = nt * 16 + quad * 4 + i;
                const float* wp = &Wd2[c * 3];
                float v0 = fmaxf(acc0[nt][i], 0.f);
                float v1 = fmaxf(acc1[nt][i], 0.f);
                p00 += v0 * wp[0]; p01 += v0 * wp[1]; p02 += v0 * wp[2];
                p10 += v1 * wp[0]; p11 += v1 * wp[1]; p12 += v1 * wp[2];
            }
        }
        p00 += __shfl_xor(p00, 16); p00 += __shfl_xor(p00, 32);
        p01 += __shfl_xor(p01, 16); p01 += __shfl_xor(p01, 32);
        p02 += __shfl_xor(p02, 16); p02 += __shfl_xor(p02, 32);
        p10 += __shfl_xor(p10, 16); p10 += __shfl_xor(p10, 32);
        p11 += __shfl_xor(p11, 16); p11 += __shfl_xor(p11, 32);
        p12 += __shfl_xor(p12, 16); p12 += __shfl_xor(p12, 32);
        if (quad == 0) {
            outp[r0 * 3 + 0] = p00 + bd2[0];
            outp[r0 * 3 + 1] = p01 + bd2[1];
            outp[r0 * 3 + 2] = p02 + bd2[2];
            if (h1) {
                outp[r1 * 3 + 0] = p10 + bd2[0];
                outp[r1 * 3 + 1] = p11 + bd2[1];
                outp[r1 * 3 + 2] = p12 + bd2[2];
            }
        }
    }
}

// ---------------- edge aggregation + gterm (merged dispatch) ----------------
// blocks [0, NN/4): one wave per destination node (edge_agg).
// blocks [NN/4, NN/4+GG): gterm for graph g = bid - NN/4.
template <int SRC>
__global__ __launch_bounds__(256) void k_edge_gterm(
    const float* __restrict__ Ps, const float* __restrict__ Pd,
    const int* __restrict__ row_ptr, const int* __restrict__ src_sorted,
    const float4* __restrict__ ea_s, const float* __restrict__ Wm1,
    float* __restrict__ accm,
    const float* __restrict__ part_a, const float* __restrict__ part_b,
    float* __restrict__ sum_hbc,
    const float* __restrict__ cnt_node, const float* __restrict__ cnt_bc,
    const float* __restrict__ Wu1, float* __restrict__ gt) {
    if (blockIdx.x >= NN / 4) {
        const int g = blockIdx.x - NN / 4;
        const int c = threadIdx.x;
        __shared__ float sg[128], sb[128];
        if (c < 128) {
            const float invn = 1.f / fmaxf(cnt_node[g], 1.f);
            const float invb = 1.f / fmaxf(cnt_bc[g], 1.f);
            float s0 = 0.f, sbv;
            if (SRC == 0) {
                float sbb = 0.f;
                for (int b = 0; b < BGRID; ++b) {
                    s0 += part_a[b * 1024 + g * 128 + c];
                    sbb += part_b[b * 1024 + g * 128 + c];
                }
                sum_hbc[g * 128 + c] = sbb;
                sbv = sbb;
            } else {
                for (int b = 0; b < BGRID; ++b) s0 += part_a[b * 1024 + g * 128 + c];
                sbv = sum_hbc[g * 128 + c];
            }
            sg[c] = s0 * invn;
            sb[c] = sbv * invb;
        }
        __syncthreads();
        if (c < 128) {
            float s = 0.f;
            for (int k = 0; k < 128; ++k) s += sg[k] * Wu1[(256 + k) * 128 + c];
            for (int k = 0; k < 128; ++k) s += sb[k] * Wu1[(384 + k) * 128 + c];
            gt[g * 128 + c] = s;
        }
        return;
    }
    const int lane = threadIdx.x & 63;
    const int d = blockIdx.x * 4 + (threadIdx.x >> 6);
    const int c = lane * 2;
    const float2 w0 = *(const float2*)&Wm1[256 * 128 + c];
    const float2 w1 = *(const float2*)&Wm1[257 * 128 + c];
    const float2 w2 = *(const float2*)&Wm1[258 * 128 + c];
    const float2 pd = *(const float2*)&Pd[(size_t)d * 128 + c];
    const int beg = row_ptr[d], end = row_ptr[d + 1];
    const float2 sv = *(const float2*)&Ps[(size_t)d * 128 + c];
    float ax = fmaxf(sv.x + pd.x, 0.f);
    float ay = fmaxf(sv.y + pd.y, 0.f);
    int k = beg;
    for (; k + 3 < end; k += 4) {
        int s0 = src_sorted[k], s1 = src_sorted[k + 1], s2 = src_sorted[k + 2], s3 = src_sorted[k + 3];
        float4 e0 = ea_s[k], e1 = ea_s[k + 1], e2 = ea_s[k + 2], e3 = ea_s[k + 3];
        float2 pa = *(const float2*)&Ps[(size_t)s0 * 128 + c];
        float2 pb = *(const float2*)&Ps[(size_t)s1 * 128 + c];
        float2 pc = *(const float2*)&Ps[(size_t)s2 * 128 + c];
        float2 pe = *(const float2*)&Ps[(size_t)s3 * 128 + c];
        ax += fmaxf(pa.x + pd.x + e0.x * w0.x + e0.y * w1.x + e0.z * w2.x, 0.f)
            + fmaxf(pb.x + pd.x + e1.x * w0.x + e1.y * w1.x + e1.z * w2.x, 0.f)
            + fmaxf(pc.x + pd.x + e2.x * w0.x + e2.y * w1.x + e2.z * w2.x, 0.f)
            + fmaxf(pe.x + pd.x + e3.x * w0.x + e3.y * w1.x + e3.z * w2.x, 0.f);
        ay += fmaxf(pa.y + pd.y + e0.x * w0.y + e0.y * w1.y + e0.z * w2.y, 0.f)
            + fmaxf(pb.y + pd.y + e1.x * w0.y + e1.y * w1.y + e1.z * w2.y, 0.f)
            + fmaxf(pc.y + pd.y + e2.x * w0.y + e2.y * w1.y + e2.z * w2.y, 0.f)
            + fmaxf(pe.y + pd.y + e3.x * w0.y + e3.y * w1.y + e3.z * w2.y, 0.f);
    }
    for (; k < end; ++k) {
        int s0 = src_sorted[k];
        float4 e0 = ea_s[k];
        float2 pa = *(const float2*)&Ps[(size_t)s0 * 128 + c];
        ax += fmaxf(pa.x + pd.x + e0.x * w0.x + e0.y * w1.x + e0.z * w2.x, 0.f);
        ay += fmaxf(pa.y + pd.y + e0.x * w0.y + e0.y * w1.y + e0.z * w2.y, 0.f);
    }
    float inv = 1.f / (float)(end - beg + 1);
    *(float2*)&accm[(size_t)d * 128 + c] = make_float2(ax * inv, ay * inv);
}

extern "C" void kernel_launch(void* const* d_in, const int* in_sizes, int n_in,
                              void* d_out, int out_size, void* d_ws, size_t ws_size,
                              hipStream_t stream) {
    const float* x = (const float*)d_in[0];
    const float* x_mask = (const float*)d_in[1];
    const float* edge_attr = (const float*)d_in[2];
    const float* W_e1 = (const float*)d_in[4];
    const float* b_e1 = (const float*)d_in[5];
    const float* W_e2 = (const float*)d_in[6];
    const float* b_e2 = (const float*)d_in[7];
    const float* W_m1 = (const float*)d_in[8];
    const float* b_m1 = (const float*)d_in[9];
    const float* W_m2 = (const float*)d_in[10];
    const float* b_m2 = (const float*)d_in[11];
    const float* W_u1 = (const float*)d_in[12];
    const float* b_u1 = (const float*)d_in[13];
    const float* W_u2 = (const float*)d_in[14];
    const float* b_u2 = (const float*)d_in[15];
    const float* W_d1 = (const float*)d_in[16];
    const float* b_d1 = (const float*)d_in[17];
    const float* W_d2 = (const float*)d_in[18];
    const float* b_d2 = (const float*)d_in[19];
    const int* edge_index = (const int*)d_in[20];
    const int* batch = (const int*)d_in[21];
    float* out = (float*)d_out;

    char* wp = (char*)d_ws;
    auto carve = [&](size_t bytes) {
        char* r = wp;
        wp += (bytes + 255) & ~(size_t)255;
        return r;
    };
    float* h = (float*)carve(sizeof(float) * (size_t)NN * 128);
    float* Ps = (float*)carve(sizeof(float) * (size_t)NN * 128);
    float* Pd = (float*)carve(sizeof(float) * (size_t)NN * 128);
    float* accm = (float*)carve(sizeof(float) * (size_t)NN * 128);
    float4* ea_s = (float4*)carve(sizeof(float4) * (size_t)EE);
    float* stats = (float*)carve(sizeof(float) * 4096);
    float* sum_hbc = stats + 1024;    // 1024
    float* cnt_node = stats + 2048;   // 8
    float* cnt_bc = stats + 2056;     // 8
    float* gterm = stats + 2304;      // 1024
    float* bfused = stats + 3328;     // 128
    float* part_h = (float*)carve(sizeof(float) * (size_t)BGRID * 1024);
    float* part_hbc = (float*)carve(sizeof(float) * (size_t)BGRID * 1024);
    float* partf = (float*)carve(sizeof(float) * (size_t)BGRID * 1024);
    int* deg = (int*)carve(sizeof(int) * NN);
    int* row_ptr = (int*)carve(sizeof(int) * (NN + 1));
    int* cursor = (int*)carve(sizeof(int) * NN);
    int* src_sorted = (int*)carve(sizeof(int) * EE);
    int* exbuf = (int*)carve(sizeof(int) * NN);
    int* blksum = (int*)carve(sizeof(int) * 256);
    float* Wf = (float*)carve(sizeof(float) * 16384);
    short* We2h = (short*)carve(sizeof(short) * 16384);
    short* We2l = (short*)carve(sizeof(short) * 16384);
    short* Wm1sh = (short*)carve(sizeof(short) * 16384);
    short* Wm1sl = (short*)carve(sizeof(short) * 16384);
    short* Wm1dh = (short*)carve(sizeof(short) * 16384);
    short* Wm1dl = (short*)carve(sizeof(short) * 16384);
    short* Wu1ah = (short*)carve(sizeof(short) * 16384);
    short* Wu1al = (short*)carve(sizeof(short) * 16384);
    short* Wfh = (short*)carve(sizeof(short) * 16384);
    short* Wfl = (short*)carve(sizeof(short) * 16384);
    short* Wu2h = (short*)carve(sizeof(short) * 16384);
    short* Wu2l = (short*)carve(sizeof(short) * 16384);
    short* Wd1h = (short*)carve(sizeof(short) * 16384);
    short* Wd1l = (short*)carve(sizeof(short) * 16384);

    const dim3 b256(256);
    const dim3 b512(512);
    const int gE256 = (EE + 255) / 256;

    hipMemsetAsync(deg, 0, sizeof(int) * NN, stream);
    hipMemsetAsync(stats, 0, sizeof(float) * 2064, stream);
    k_wfuse<<<65, b256, 0, stream>>>(W_m2, W_u1, b_m2, b_u1, Wf, bfused);
    k_pack_all<<<448, b256, 0, stream>>>(W_e2, W_m1, W_u1, Wf, W_u2, W_d1,
                                         We2h, We2l, Wm1sh, Wm1sl, Wm1dh, Wm1dl,
                                         Wu1ah, Wu1al, Wfh, Wfl, Wu2h, Wu2l, Wd1h, Wd1l);
    // CSR
    k_count<<<gE256, b256, 0, stream>>>(edge_index, deg);
    k_scan1<<<NBLK, b256, 0, stream>>>(deg, exbuf, blksum);
    k_scan2<<<1, b256, 0, stream>>>(blksum);
    k_scan3<<<NBLK, b256, 0, stream>>>(exbuf, blksum, row_ptr, cursor);
    k_scatter<<<gE256, b256, 0, stream>>>(edge_index, edge_attr, cursor, src_sorted, ea_s);
    k_counts<<<NBLK, b256, 0, stream>>>(batch, x_mask, cnt_node, cnt_bc);
    // fused encoder: h + Ps + Pd + partial stats (512-thread blocks)
    k_genc<<<BGRID, b512, 0, stream>>>(x, x_mask, W_e1, b_e1, We2h, We2l, b_e2,
                                       Wm1sh, Wm1sl, Wm1dh, Wm1dl, b_m1, batch,
                                       h, Ps, Pd, part_h, part_hbc);

    const int EGRID = NN / 4 + GG;
    for (int rep = 0; rep < 3; ++rep) {
        if (rep == 0)
            k_edge_gterm<0><<<EGRID, b256, 0, stream>>>(Ps, Pd, row_ptr, src_sorted, ea_s, W_m1, accm,
                                                        part_h, part_hbc, sum_hbc, cnt_node, cnt_bc,
                                                        W_u1, gterm);
        else
            k_edge_gterm<1><<<EGRID, b256, 0, stream>>>(Ps, Pd, row_ptr, src_sorted, ea_s, W_m1, accm,
                                                        partf, nullptr, sum_hbc, cnt_node, cnt_bc,
                                                        W_u1, gterm);
        if (rep < 2) {
            k_fused3<0><<<BGRID, b512, 0, stream>>>(h, accm, Wu1ah, Wu1al, Wfh, Wfl, Wu2h, Wu2l,
                                                    Wm1sh, Wm1sl, Wm1dh, Wm1dl,
                                                    gterm, bfused, b_u2, b_m1, nullptr, nullptr,
                                                    nullptr, batch, h, Ps, Pd, partf, nullptr);
        } else {
            k_fused3<1><<<BGRID, b512, 0, stream>>>(h, accm, Wu1ah, Wu1al, Wfh, Wfl, Wu2h, Wu2l,
                                                    nullptr, nullptr, Wd1h, Wd1l,
                                                    gterm, bfused, b_u2, nullptr, b_d1, W_d2,
                                                    b_d2, batch, nullptr, nullptr, nullptr,
                                                    nullptr, out);
        }
    }
}

// Round 11
// 595.502 us; speedup vs baseline: 1.7854x; 1.7854x over previous
//
#include <hip/hip_runtime.h>

// EPD GNN, r22. r21 regressed because __launch_bounds__(512,4) capped VGPR at 64
// -> scratch spill (FETCH/WRITE doubled, genc 96->250us). Fix: (512,2) -> VGPR
// cap 256, compiler allocates natural ~128 (as in r20), no spill. 512-thread
// blocks keep the halved per-wave W-staging; residency >= r20's 8 waves/CU.
// Everything else identical to r20/r21.

#define NN 50000
#define EE 400000
#define GG 8
#define NBLK 196   // ceil(NN/256)
#define BGRID 256  // 512-thread kernels: 2048 waves over 3125 tiles

typedef __attribute__((ext_vector_type(8))) short short8;
typedef __attribute__((ext_vector_type(4))) float floatx4;

__device__ __forceinline__ unsigned short f2bf(float x) {
    unsigned u = __float_as_uint(x);
    u += 0x7FFF + ((u >> 16) & 1);
    return (unsigned short)(u >> 16);
}
__device__ __forceinline__ float bf2f(unsigned short h) {
    return __uint_as_float(((unsigned)h) << 16);
}
__device__ __forceinline__ void cvt8(const float* v, short8& hi, short8& lo) {
#pragma unroll
    for (int j = 0; j < 8; ++j) {
        unsigned short h = f2bf(v[j]);
        hi[j] = (short)h;
        lo[j] = (short)f2bf(v[j] - bf2f(h));
    }
}

// ---------------- CSR build ----------------
__global__ void k_count(const int* __restrict__ ei, int* __restrict__ deg) {
    int i = blockIdx.x * 256 + threadIdx.x;
    if (i < EE) atomicAdd(&deg[ei[EE + i]], 1);
}

__global__ __launch_bounds__(256) void k_scan1(const int* __restrict__ deg, int* __restrict__ ex,
                                               int* __restrict__ blksum) {
    __shared__ int s[256];
    const int t = threadIdx.x;
    int i = blockIdx.x * 256 + t;
    int v = (i < NN) ? deg[i] : 0;
    s[t] = v;
    __syncthreads();
    for (int off = 1; off < 256; off <<= 1) {
        int x = (t >= off) ? s[t - off] : 0;
        __syncthreads();
        s[t] += x;
        __syncthreads();
    }
    if (i < NN) ex[i] = s[t] - v;
    if (t == 255) blksum[blockIdx.x] = s[255];
}

__global__ __launch_bounds__(256) void k_scan2(int* __restrict__ blksum) {
    __shared__ int s[256];
    const int t = threadIdx.x;
    int v = (t < NBLK) ? blksum[t] : 0;
    s[t] = v;
    __syncthreads();
    for (int off = 1; off < 256; off <<= 1) {
        int x = (t >= off) ? s[t - off] : 0;
        __syncthreads();
        s[t] += x;
        __syncthreads();
    }
    if (t < NBLK) blksum[t] = s[t] - v;
}

__global__ void k_scan3(const int* __restrict__ ex, const int* __restrict__ blkoff,
                        int* __restrict__ row_ptr, int* __restrict__ cursor) {
    int i = blockIdx.x * 256 + threadIdx.x;
    if (i < NN) {
        int v = ex[i] + blkoff[blockIdx.x];
        row_ptr[i] = v;
        cursor[i] = v;
    }
    if (i == 0) row_ptr[NN] = EE;
}

__global__ void k_scatter(const int* __restrict__ ei, const float* __restrict__ ea,
                          int* __restrict__ cursor, int* __restrict__ src_sorted,
                          float4* __restrict__ ea_s) {
    int e = blockIdx.x * 256 + threadIdx.x;
    if (e >= EE) return;
    int s = ei[e], d = ei[EE + e];
    int p = atomicAdd(&cursor[d], 1);
    src_sorted[p] = s;
    ea_s[p] = make_float4(ea[3 * e], ea[3 * e + 1], ea[3 * e + 2], 0.f);
}

// ---------------- per-graph counts (once): cnt_node, cnt_bc ----------------
__global__ __launch_bounds__(256) void k_counts(const int* __restrict__ batch, const float* __restrict__ xm,
                                                float* __restrict__ cnt_node, float* __restrict__ cnt_bc) {
    __shared__ float cn[8], cb[8];
    const int t = threadIdx.x;
    if (t < 8) { cn[t] = 0.f; cb[t] = 0.f; }
    __syncthreads();
    int i = blockIdx.x * 256 + t;
    if (i < NN) {
        int g = batch[i];
        atomicAdd(&cn[g], 1.f);
        atomicAdd(&cb[g], xm[3 * i + 2]);
    }
    __syncthreads();
    if (t < 8) {
        if (cn[t] != 0.f) atomicAdd(&cnt_node[t], cn[t]);
        if (cb[t] != 0.f) atomicAdd(&cnt_bc[t], cb[t]);
    }
}

// ---------------- weight fusion (block 64 = bfuse): Wf = Wm2 @ Wu1[128:256], bf = bu1 + bm2 @ Wu1[128:256] ----------------
__global__ __launch_bounds__(256) void k_wfuse(const float* __restrict__ Wm2, const float* __restrict__ Wu1,
                                               const float* __restrict__ bm2, const float* __restrict__ bu1,
                                               float* __restrict__ Wf, float* __restrict__ bf) {
    if (blockIdx.x == 64) {
        int c = threadIdx.x;
        if (c < 128) {
            float s = bu1[c];
            for (int k = 0; k < 128; ++k) s += bm2[k] * Wu1[(128 + k) * 128 + c];
            bf[c] = s;
        }
        return;
    }
    int idx = blockIdx.x * 256 + threadIdx.x;   // 16384
    int r = idx >> 7, c = idx & 127;
    float s = 0.f;
    for (int k = 0; k < 128; ++k) s += Wm2[r * 128 + k] * Wu1[(128 + k) * 128 + c];
    Wf[idx] = s;
}

// ---------------- weight packing ----------------
// normal (ids 0,3,4):  k = k0*32 + quad*8 + j
// permuted (ids 1,2,5,6): k = k0*32 + 16*(j>>2) + 4*quad + (j&3)
__global__ __launch_bounds__(256) void k_pack_all(
    const float* __restrict__ We2, const float* __restrict__ Wm1,
    const float* __restrict__ Wu1, const float* __restrict__ Wf,
    const float* __restrict__ Wu2, const float* __restrict__ Wd1,
    short* __restrict__ We2h, short* __restrict__ We2l,
    short* __restrict__ Wm1sh, short* __restrict__ Wm1sl,
    short* __restrict__ Wm1dh, short* __restrict__ Wm1dl,
    short* __restrict__ Wu1ah, short* __restrict__ Wu1al,
    short* __restrict__ Wfh, short* __restrict__ Wfl,
    short* __restrict__ Wu2h, short* __restrict__ Wu2l,
    short* __restrict__ Wd1h, short* __restrict__ Wd1l) {
    int b = blockIdx.x;
    int id = b >> 6;
    int p = (b & 63) * 256 + threadIdx.x;   // 0..16383
    const float* W;
    short *hi, *lo;
    switch (id) {
        case 0: W = We2; hi = We2h; lo = We2l; break;
        case 1: W = Wm1; hi = Wm1sh; lo = Wm1sl; break;
        case 2: W = Wm1 + 16384; hi = Wm1dh; lo = Wm1dl; break;
        case 3: W = Wu1; hi = Wu1ah; lo = Wu1al; break;
        case 4: W = Wf; hi = Wfh; lo = Wfl; break;
        case 5: W = Wu2; hi = Wu2h; lo = Wu2l; break;
        default: W = Wd1; hi = Wd1h; lo = Wd1l; break;
    }
    int j = p & 7;
    int lane = (p >> 3) & 63;
    int chunk = p >> 9;          // 0..31
    int k0 = chunk & 3, nt = chunk >> 2;
    int quad = lane >> 4;
    int n = nt * 16 + (lane & 15);
    bool perm = (id == 1) || (id == 2) || (id == 5) || (id == 6);
    int k;
    if (perm) k = k0 * 32 + ((j >> 2) << 4) + (quad << 2) + (j & 3);
    else k = k0 * 32 + quad * 8 + j;
    float w = W[k * 128 + n];
    unsigned short h = f2bf(w);
    hi[p] = (short)h;
    lo[p] = (short)f2bf(w - bf2f(h));
}

// ---------------- fused encoder (512 threads): h, Ps, Pd (+ partial stats) ----------------
__global__ __launch_bounds__(512, 2) void k_genc(
    const float* __restrict__ x, const float* __restrict__ xm,
    const float* __restrict__ We1, const float* __restrict__ be1,
    const short* __restrict__ W2h, const short* __restrict__ W2l,
    const float* __restrict__ be2,
    const short* __restrict__ Wsh, const short* __restrict__ Wsl,
    const short* __restrict__ Wdh, const short* __restrict__ Wdl,
    const float* __restrict__ bm1, const int* __restrict__ batch,
    float* __restrict__ hout, float* __restrict__ Ps, float* __restrict__ Pd,
    float* __restrict__ part_h, float* __restrict__ part_hbc) {
    __shared__ __align__(16) short sWh[16384];
    __shared__ __align__(16) short sWl[16384];
    __shared__ __align__(16) float swe[1024];   // native We1 layout [kk][c]
    __shared__ float sbe[128];
    __shared__ float ldsH[1024];
    __shared__ float ldsB[1024];
    const int tid = threadIdx.x;
    const int wave = tid >> 6, lane = tid & 63;
    const int m16 = lane & 15, quad = lane >> 4;
    const int t0 = blockIdx.x * 8 + wave;      // 0..2047
    const int t1 = t0 + BGRID * 8;             // 2048..4095
    const bool h1 = (t1 < 3125);
    const int r0 = t0 * 16 + m16;
    const int r1 = (h1 ? t1 * 16 : 0) + m16;

    auto copyW = [&](const short* gh, const short* gl) {
        const float4* sH = (const float4*)gh;
        const float4* sL = (const float4*)gl;
        float4* dH = (float4*)sWh;
        float4* dL = (float4*)sWl;
#pragma unroll
        for (int u = 0; u < 4; ++u) {
            int i = tid + u * 512;
            dH[i] = sH[i];
            dL[i] = sL[i];
        }
    };

    {
        copyW(W2h, W2l);
        for (int i = tid; i < 1024; i += 512) {
            swe[i] = We1[i];
            ldsH[i] = 0.f;
            ldsB[i] = 0.f;
        }
        if (tid < 128) sbe[tid] = be1[tid];
    }
    float in0[8], in1[8];
#pragma unroll
    for (int k = 0; k < 5; ++k) { in0[k] = x[r0 * 5 + k]; in1[k] = x[r1 * 5 + k]; }
#pragma unroll
    for (int k = 0; k < 3; ++k) { in0[5 + k] = xm[r0 * 3 + k]; in1[5 + k] = xm[r1 * 3 + k]; }
    int g0 = batch[r0], g1 = batch[r1];
    __syncthreads();
    // enc1 outputs in A-fragment slot order: c = k0*32 + quad*8 + j
    short8 ah0[4], al0[4], ah1[4], al1[4];
#pragma unroll
    for (int k0 = 0; k0 < 4; ++k0) {
        float tv[8];
#pragma unroll
        for (int j = 0; j < 8; ++j) {
            int c = k0 * 32 + quad * 8 + j;
            float s = sbe[c];
#pragma unroll
            for (int kk = 0; kk < 8; ++kk) s += in0[kk] * swe[kk * 128 + c];
            tv[j] = fmaxf(s, 0.f);
        }
        cvt8(tv, ah0[k0], al0[k0]);
    }
#pragma unroll
    for (int k0 = 0; k0 < 4; ++k0) {
        float tv[8];
#pragma unroll
        for (int j = 0; j < 8; ++j) {
            int c = k0 * 32 + quad * 8 + j;
            float s = sbe[c];
#pragma unroll
            for (int kk = 0; kk < 8; ++kk) s += in1[kk] * swe[kk * 128 + c];
            tv[j] = fmaxf(s, 0.f);
        }
        cvt8(tv, ah1[k0], al1[k0]);
    }
    const int fb = lane << 3;
    floatx4 acc0[8], acc1[8];
    auto mmacc = [&](const short8 xh0[4], const short8 xl0[4],
                     const short8 xh1[4], const short8 xl1[4]) {
#pragma unroll
        for (int k0 = 0; k0 < 4; ++k0) {
#pragma unroll
            for (int nt = 0; nt < 8; ++nt) {
                const int base = (((nt << 2) | k0) << 9) + fb;
                short8 bh = *(const short8*)&sWh[base];
                short8 bl = *(const short8*)&sWl[base];
                acc0[nt] = __builtin_amdgcn_mfma_f32_16x16x32_bf16(bh, xh0[k0], acc0[nt], 0, 0, 0);
                acc0[nt] = __builtin_amdgcn_mfma_f32_16x16x32_bf16(bl, xh0[k0], acc0[nt], 0, 0, 0);
                acc0[nt] = __builtin_amdgcn_mfma_f32_16x16x32_bf16(bh, xl0[k0], acc0[nt], 0, 0, 0);
                if (h1) {
                    acc1[nt] = __builtin_amdgcn_mfma_f32_16x16x32_bf16(bh, xh1[k0], acc1[nt], 0, 0, 0);
                    acc1[nt] = __builtin_amdgcn_mfma_f32_16x16x32_bf16(bl, xh1[k0], acc1[nt], 0, 0, 0);
                    acc1[nt] = __builtin_amdgcn_mfma_f32_16x16x32_bf16(bh, xl1[k0], acc1[nt], 0, 0, 0);
                }
            }
        }
    };

    // h = enc1@We2 + be2 (seeded)
#pragma unroll
    for (int nt = 0; nt < 8; ++nt) {
        float4 bv = *(const float4*)(be2 + nt * 16 + quad * 4);
        acc0[nt][0] = bv.x; acc0[nt][1] = bv.y; acc0[nt][2] = bv.z; acc0[nt][3] = bv.w;
        acc1[nt][0] = bv.x; acc1[nt][1] = bv.y; acc1[nt][2] = bv.z; acc1[nt][3] = bv.w;
    }
    mmacc(ah0, al0, ah1, al1);
    {
        float* d0 = hout + (size_t)r0 * 128 + quad * 4;
#pragma unroll
        for (int nt = 0; nt < 8; ++nt)
            *(float4*)(d0 + nt * 16) = make_float4(acc0[nt][0], acc0[nt][1], acc0[nt][2], acc0[nt][3]);
    }
    if (h1) {
        float* d1 = hout + (size_t)r1 * 128 + quad * 4;
#pragma unroll
        for (int nt = 0; nt < 8; ++nt)
            *(float4*)(d1 + nt * 16) = make_float4(acc1[nt][0], acc1[nt][1], acc1[nt][2], acc1[nt][3]);
    }
    // stats -> LDS accumulators
    {
        float bc = in0[7];
        int glo = __shfl(g0, 0), ghi = __shfl(g0, 15);
        if (glo == ghi) {
#pragma unroll
            for (int nt = 0; nt < 8; ++nt) {
                float4 v = make_float4(acc0[nt][0], acc0[nt][1], acc0[nt][2], acc0[nt][3]);
                float4 w = make_float4(v.x * bc, v.y * bc, v.z * bc, v.w * bc);
#pragma unroll
                for (int off = 1; off < 16; off <<= 1) {
                    v.x += __shfl_xor(v.x, off); v.y += __shfl_xor(v.y, off);
                    v.z += __shfl_xor(v.z, off); v.w += __shfl_xor(v.w, off);
                    w.x += __shfl_xor(w.x, off); w.y += __shfl_xor(w.y, off);
                    w.z += __shfl_xor(w.z, off); w.w += __shfl_xor(w.w, off);
                }
                if (m16 == 0) {
                    float* sp = &ldsH[glo * 128 + nt * 16 + quad * 4];
                    atomicAdd(sp + 0, v.x); atomicAdd(sp + 1, v.y);
                    atomicAdd(sp + 2, v.z); atomicAdd(sp + 3, v.w);
                    float* sq = &ldsB[glo * 128 + nt * 16 + quad * 4];
                    atomicAdd(sq + 0, w.x); atomicAdd(sq + 1, w.y);
                    atomicAdd(sq + 2, w.z); atomicAdd(sq + 3, w.w);
                }
            }
        } else {
#pragma unroll
            for (int nt = 0; nt < 8; ++nt)
#pragma unroll
                for (int i = 0; i < 4; ++i) {
                    atomicAdd(&ldsH[g0 * 128 + nt * 16 + quad * 4 + i], acc0[nt][i]);
                    atomicAdd(&ldsB[g0 * 128 + nt * 16 + quad * 4 + i], acc0[nt][i] * bc);
                }
        }
    }
    if (h1) {
        float bc = in1[7];
        int glo = __shfl(g1, 0), ghi = __shfl(g1, 15);
        if (glo == ghi) {
#pragma unroll
            for (int nt = 0; nt < 8; ++nt) {
                float4 v = make_float4(acc1[nt][0], acc1[nt][1], acc1[nt][2], acc1[nt][3]);
                float4 w = make_float4(v.x * bc, v.y * bc, v.z * bc, v.w * bc);
#pragma unroll
                for (int off = 1; off < 16; off <<= 1) {
                    v.x += __shfl_xor(v.x, off); v.y += __shfl_xor(v.y, off);
                    v.z += __shfl_xor(v.z, off); v.w += __shfl_xor(v.w, off);
                    w.x += __shfl_xor(w.x, off); w.y += __shfl_xor(w.y, off);
                    w.z += __shfl_xor(w.z, off); w.w += __shfl_xor(w.w, off);
                }
                if (m16 == 0) {
                    float* sp = &ldsH[glo * 128 + nt * 16 + quad * 4];
                    atomicAdd(sp + 0, v.x); atomicAdd(sp + 1, v.y);
                    atomicAdd(sp + 2, v.z); atomicAdd(sp + 3, v.w);
                    float* sq = &ldsB[glo * 128 + nt * 16 + quad * 4];
                    atomicAdd(sq + 0, w.x); atomicAdd(sq + 1, w.y);
                    atomicAdd(sq + 2, w.z); atomicAdd(sq + 3, w.w);
                }
            }
        } else {
#pragma unroll
            for (int nt = 0; nt < 8; ++nt)
#pragma unroll
                for (int i = 0; i < 4; ++i) {
                    atomicAdd(&ldsH[g1 * 128 + nt * 16 + quad * 4 + i], acc1[nt][i]);
                    atomicAdd(&ldsB[g1 * 128 + nt * 16 + quad * 4 + i], acc1[nt][i] * bc);
                }
        }
    }
    // convert in-register h -> permuted A-fragments
    short8 ph0[4], pl0[4], ph1[4], pl1[4];
#pragma unroll
    for (int k0 = 0; k0 < 4; ++k0) {
        float v[8] = {acc0[2 * k0][0], acc0[2 * k0][1], acc0[2 * k0][2], acc0[2 * k0][3],
                      acc0[2 * k0 + 1][0], acc0[2 * k0 + 1][1], acc0[2 * k0 + 1][2], acc0[2 * k0 + 1][3]};
        cvt8(v, ph0[k0], pl0[k0]);
    }
#pragma unroll
    for (int k0 = 0; k0 < 4; ++k0) {
        float v[8] = {acc1[2 * k0][0], acc1[2 * k0][1], acc1[2 * k0][2], acc1[2 * k0][3],
                      acc1[2 * k0 + 1][0], acc1[2 * k0 + 1][1], acc1[2 * k0 + 1][2], acc1[2 * k0 + 1][3]};
        cvt8(v, ph1[k0], pl1[k0]);
    }
    __syncthreads();
    // dense per-block partial store (after sync: all LDS atomics landed)
    {
        float* ph = part_h + (size_t)blockIdx.x * 1024;
        float* pb = part_hbc + (size_t)blockIdx.x * 1024;
        for (int i = tid; i < 1024; i += 512) { ph[i] = ldsH[i]; pb[i] = ldsB[i]; }
    }
    // Ps = h@Wm1sp
    copyW(Wsh, Wsl);
    __syncthreads();
#pragma unroll
    for (int nt = 0; nt < 8; ++nt) { acc0[nt] = (floatx4)0.f; acc1[nt] = (floatx4)0.f; }
    mmacc(ph0, pl0, ph1, pl1);
    {
        float* d0 = Ps + (size_t)r0 * 128 + quad * 4;
#pragma unroll
        for (int nt = 0; nt < 8; ++nt)
            *(float4*)(d0 + nt * 16) = make_float4(acc0[nt][0], acc0[nt][1], acc0[nt][2], acc0[nt][3]);
        if (h1) {
            float* d1 = Ps + (size_t)r1 * 128 + quad * 4;
#pragma unroll
            for (int nt = 0; nt < 8; ++nt)
                *(float4*)(d1 + nt * 16) = make_float4(acc1[nt][0], acc1[nt][1], acc1[nt][2], acc1[nt][3]);
        }
    }
    // Pd = h@Wm1dp + bm1 (seeded)
    __syncthreads();
    copyW(Wdh, Wdl);
    __syncthreads();
#pragma unroll
    for (int nt = 0; nt < 8; ++nt) {
        float4 bv = *(const float4*)(bm1 + nt * 16 + quad * 4);
        acc0[nt][0] = bv.x; acc0[nt][1] = bv.y; acc0[nt][2] = bv.z; acc0[nt][3] = bv.w;
        acc1[nt][0] = bv.x; acc1[nt][1] = bv.y; acc1[nt][2] = bv.z; acc1[nt][3] = bv.w;
    }
    mmacc(ph0, pl0, ph1, pl1);
    {
        float* d0 = Pd + (size_t)r0 * 128 + quad * 4;
#pragma unroll
        for (int nt = 0; nt < 8; ++nt)
            *(float4*)(d0 + nt * 16) = make_float4(acc0[nt][0], acc0[nt][1], acc0[nt][2], acc0[nt][3]);
        if (h1) {
            float* d1 = Pd + (size_t)r1 * 128 + quad * 4;
#pragma unroll
            for (int nt = 0; nt < 8; ++nt)
                *(float4*)(d1 + nt * 16) = make_float4(acc1[nt][0], acc1[nt][1], acc1[nt][2], acc1[nt][3]);
        }
    }
}

// ---------------- FUSED3 (512 threads, 2-tile): tmp=h@Wu1a+gt+bf ; pre=relu(tmp+accm@Wf) ; h'=h+pre@Wu2p ;
// MODE 0 (EMIT): store h', stats->partf, Ps=h'@Wm1sp, Pd=h'@Wm1dp+bm1
// MODE 1 (DEC):  out = relu(h'@Wd1p + bd1) @ Wd2 + bd2   (h' never stored)
template <int MODE>
__global__ __launch_bounds__(512, 2) void k_fused3(
    const float* __restrict__ hbuf, const float* __restrict__ accm,
    const short* __restrict__ W1h, const short* __restrict__ W1l,
    const short* __restrict__ W2h, const short* __restrict__ W2l,
    const short* __restrict__ W3h, const short* __restrict__ W3l,
    const short* __restrict__ Wsh, const short* __restrict__ Wsl,
    const short* __restrict__ Wdh, const short* __restrict__ Wdl,
    const float* __restrict__ gt, const float* __restrict__ bf3,
    const float* __restrict__ bu2, const float* __restrict__ bm1,
    const float* __restrict__ bd1, const float* __restrict__ Wd2,
    const float* __restrict__ bd2, const int* __restrict__ batch,
    float* __restrict__ hout, float* __restrict__ Ps, float* __restrict__ Pd,
    float* __restrict__ partf, float* __restrict__ outp) {
    __shared__ __align__(16) short sWh[16384];
    __shared__ __align__(16) short sWl[16384];
    __shared__ float ldsH[1024];
    const int tid = threadIdx.x;
    const int wave = tid >> 6, lane = tid & 63;
    const int m16 = lane & 15, quad = lane >> 4;
    const int t0 = blockIdx.x * 8 + wave;
    const int t1 = t0 + BGRID * 8;
    const bool h1 = (t1 < 3125);
    const int r0 = t0 * 16 + m16;
    const int r1 = (h1 ? t1 * 16 : 0) + m16;

    auto copyW = [&](const short* gh, const short* gl) {
        const float4* sH = (const float4*)gh;
        const float4* sL = (const float4*)gl;
        float4* dH = (float4*)sWh;
        float4* dL = (float4*)sWl;
#pragma unroll
        for (int u = 0; u < 4; ++u) {
            int i = tid + u * 512;
            dH[i] = sH[i];
            dL[i] = sL[i];
        }
    };

    const float* Ap0 = hbuf + (size_t)r0 * 128 + quad * 8;
    const float* Ap1 = hbuf + (size_t)r1 * 128 + quad * 8;
    float4 a0[8], a1[8];
#pragma unroll
    for (int k0 = 0; k0 < 4; ++k0) {
        a0[k0 * 2 + 0] = *(const float4*)(Ap0 + k0 * 32);
        a0[k0 * 2 + 1] = *(const float4*)(Ap0 + k0 * 32 + 4);
        a1[k0 * 2 + 0] = *(const float4*)(Ap1 + k0 * 32);
        a1[k0 * 2 + 1] = *(const float4*)(Ap1 + k0 * 32 + 4);
    }
    int g0 = batch[r0], g1 = batch[r1];
    if (MODE == 0) {
        for (int i = tid; i < 1024; i += 512) ldsH[i] = 0.f;
    }
    copyW(W1h, W1l);
    __syncthreads();

    short8 hh0[4], hl0[4], hh1[4], hl1[4];
#pragma unroll
    for (int k0 = 0; k0 < 4; ++k0) {
        float v[8] = {a0[k0 * 2].x, a0[k0 * 2].y, a0[k0 * 2].z, a0[k0 * 2].w,
                      a0[k0 * 2 + 1].x, a0[k0 * 2 + 1].y, a0[k0 * 2 + 1].z, a0[k0 * 2 + 1].w};
        cvt8(v, hh0[k0], hl0[k0]);
    }
#pragma unroll
    for (int k0 = 0; k0 < 4; ++k0) {
        float v[8] = {a1[k0 * 2].x, a1[k0 * 2].y, a1[k0 * 2].z, a1[k0 * 2].w,
                      a1[k0 * 2 + 1].x, a1[k0 * 2 + 1].y, a1[k0 * 2 + 1].z, a1[k0 * 2 + 1].w};
        cvt8(v, hh1[k0], hl1[k0]);
    }

    const int fb = lane << 3;
    floatx4 acc0[8], acc1[8];
    auto mmacc = [&](const short8 xh0[4], const short8 xl0[4],
                     const short8 xh1[4], const short8 xl1[4]) {
#pragma unroll
        for (int k0 = 0; k0 < 4; ++k0) {
#pragma unroll
            for (int nt = 0; nt < 8; ++nt) {
                const int base = (((nt << 2) | k0) << 9) + fb;
                short8 bh = *(const short8*)&sWh[base];
                short8 bl = *(const short8*)&sWl[base];
                acc0[nt] = __builtin_amdgcn_mfma_f32_16x16x32_bf16(bh, xh0[k0], acc0[nt], 0, 0, 0);
                acc0[nt] = __builtin_amdgcn_mfma_f32_16x16x32_bf16(bl, xh0[k0], acc0[nt], 0, 0, 0);
                acc0[nt] = __builtin_amdgcn_mfma_f32_16x16x32_bf16(bh, xl0[k0], acc0[nt], 0, 0, 0);
                if (h1) {
                    acc1[nt] = __builtin_amdgcn_mfma_f32_16x16x32_bf16(bh, xh1[k0], acc1[nt], 0, 0, 0);
                    acc1[nt] = __builtin_amdgcn_mfma_f32_16x16x32_bf16(bl, xh1[k0], acc1[nt], 0, 0, 0);
                    acc1[nt] = __builtin_amdgcn_mfma_f32_16x16x32_bf16(bh, xl1[k0], acc1[nt], 0, 0, 0);
                }
            }
        }
    };

    // gemm1: acc = bf + gt[g] + h@Wu1a  -> tmp
    {
        const float* gp0 = gt + g0 * 128 + quad * 4;
        const float* gp1 = gt + g1 * 128 + quad * 4;
#pragma unroll
        for (int nt = 0; nt < 8; ++nt) {
            float4 bv = *(const float4*)(bf3 + nt * 16 + quad * 4);
            float4 gv0 = *(const float4*)(gp0 + nt * 16);
            float4 gv1 = *(const float4*)(gp1 + nt * 16);
            acc0[nt][0] = bv.x + gv0.x; acc0[nt][1] = bv.y + gv0.y;
            acc0[nt][2] = bv.z + gv0.z; acc0[nt][3] = bv.w + gv0.w;
            acc1[nt][0] = bv.x + gv1.x; acc1[nt][1] = bv.y + gv1.y;
            acc1[nt][2] = bv.z + gv1.z; acc1[nt][3] = bv.w + gv1.w;
        }
    }
    mmacc(hh0, hl0, hh1, hl1);

    // accm loads (latency hides under W2 stage + sync)
    const float* Cp0 = accm + (size_t)r0 * 128 + quad * 8;
    const float* Cp1 = accm + (size_t)r1 * 128 + quad * 8;
    float4 c0[8], c1[8];
#pragma unroll
    for (int k0 = 0; k0 < 4; ++k0) {
        c0[k0 * 2 + 0] = *(const float4*)(Cp0 + k0 * 32);
        c0[k0 * 2 + 1] = *(const float4*)(Cp0 + k0 * 32 + 4);
        c1[k0 * 2 + 0] = *(const float4*)(Cp1 + k0 * 32);
        c1[k0 * 2 + 1] = *(const float4*)(Cp1 + k0 * 32 + 4);
    }
    __syncthreads();
    copyW(W2h, W2l);
    __syncthreads();

    short8 ch0[4], cl0[4], ch1[4], cl1[4];
#pragma unroll
    for (int k0 = 0; k0 < 4; ++k0) {
        float v[8] = {c0[k0 * 2].x, c0[k0 * 2].y, c0[k0 * 2].z, c0[k0 * 2].w,
                      c0[k0 * 2 + 1].x, c0[k0 * 2 + 1].y, c0[k0 * 2 + 1].z, c0[k0 * 2 + 1].w};
        cvt8(v, ch0[k0], cl0[k0]);
    }
#pragma unroll
    for (int k0 = 0; k0 < 4; ++k0) {
        float v[8] = {c1[k0 * 2].x, c1[k0 * 2].y, c1[k0 * 2].z, c1[k0 * 2].w,
                      c1[k0 * 2 + 1].x, c1[k0 * 2 + 1].y, c1[k0 * 2 + 1].z, c1[k0 * 2 + 1].w};
        cvt8(v, ch1[k0], cl1[k0]);
    }
    // gemm2: acc += accm@Wf -> pre = relu(acc)
    mmacc(ch0, cl0, ch1, cl1);

    short8 ph0[4], pl0[4], ph1[4], pl1[4];
#pragma unroll
    for (int k0 = 0; k0 < 4; ++k0) {
        float v[8] = {fmaxf(acc0[2 * k0][0], 0.f), fmaxf(acc0[2 * k0][1], 0.f),
                      fmaxf(acc0[2 * k0][2], 0.f), fmaxf(acc0[2 * k0][3], 0.f),
                      fmaxf(acc0[2 * k0 + 1][0], 0.f), fmaxf(acc0[2 * k0 + 1][1], 0.f),
                      fmaxf(acc0[2 * k0 + 1][2], 0.f), fmaxf(acc0[2 * k0 + 1][3], 0.f)};
        cvt8(v, ph0[k0], pl0[k0]);
    }
#pragma unroll
    for (int k0 = 0; k0 < 4; ++k0) {
        float v[8] = {fmaxf(acc1[2 * k0][0], 0.f), fmaxf(acc1[2 * k0][1], 0.f),
                      fmaxf(acc1[2 * k0][2], 0.f), fmaxf(acc1[2 * k0][3], 0.f),
                      fmaxf(acc1[2 * k0 + 1][0], 0.f), fmaxf(acc1[2 * k0 + 1][1], 0.f),
                      fmaxf(acc1[2 * k0 + 1][2], 0.f), fmaxf(acc1[2 * k0 + 1][3], 0.f)};
        cvt8(v, ph1[k0], pl1[k0]);
    }

    // re-seed acc = h + bu2 (epilogue layout, memory re-read)
    {
        const float* Ep0 = hbuf + (size_t)r0 * 128 + quad * 4;
        const float* Ep1 = hbuf + (size_t)r1 * 128 + quad * 4;
#pragma unroll
        for (int nt = 0; nt < 8; ++nt) {
            float4 bv = *(const float4*)(bu2 + nt * 16 + quad * 4);
            float4 e0 = *(const float4*)(Ep0 + nt * 16);
            float4 e1 = *(const float4*)(Ep1 + nt * 16);
            acc0[nt][0] = e0.x + bv.x; acc0[nt][1] = e0.y + bv.y;
            acc0[nt][2] = e0.z + bv.z; acc0[nt][3] = e0.w + bv.w;
            acc1[nt][0] = e1.x + bv.x; acc1[nt][1] = e1.y + bv.y;
            acc1[nt][2] = e1.z + bv.z; acc1[nt][3] = e1.w + bv.w;
        }
    }
    __syncthreads();
    copyW(W3h, W3l);
    __syncthreads();
    // gemm3: acc += pre@Wu2p -> h'
    mmacc(ph0, pl0, ph1, pl1);

    if (MODE == 0) {
        // store h'
        {
            float* d0 = hout + (size_t)r0 * 128 + quad * 4;
#pragma unroll
            for (int nt = 0; nt < 8; ++nt)
                *(float4*)(d0 + nt * 16) = make_float4(acc0[nt][0], acc0[nt][1], acc0[nt][2], acc0[nt][3]);
        }
        if (h1) {
            float* d1 = hout + (size_t)r1 * 128 + quad * 4;
#pragma unroll
            for (int nt = 0; nt < 8; ++nt)
                *(float4*)(d1 + nt * 16) = make_float4(acc1[nt][0], acc1[nt][1], acc1[nt][2], acc1[nt][3]);
        }
        // stats
        {
            int glo = __shfl(g0, 0), ghi = __shfl(g0, 15);
            if (glo == ghi) {
#pragma unroll
                for (int nt = 0; nt < 8; ++nt) {
                    float4 v = make_float4(acc0[nt][0], acc0[nt][1], acc0[nt][2], acc0[nt][3]);
#pragma unroll
                    for (int off = 1; off < 16; off <<= 1) {
                        v.x += __shfl_xor(v.x, off);
                        v.y += __shfl_xor(v.y, off);
                        v.z += __shfl_xor(v.z, off);
                        v.w += __shfl_xor(v.w, off);
                    }
                    if (m16 == 0) {
                        float* sp = &ldsH[glo * 128 + nt * 16 + quad * 4];
                        atomicAdd(sp + 0, v.x); atomicAdd(sp + 1, v.y);
                        atomicAdd(sp + 2, v.z); atomicAdd(sp + 3, v.w);
                    }
                }
            } else {
#pragma unroll
                for (int nt = 0; nt < 8; ++nt)
#pragma unroll
                    for (int i = 0; i < 4; ++i)
                        atomicAdd(&ldsH[g0 * 128 + nt * 16 + quad * 4 + i], acc0[nt][i]);
            }
        }
        if (h1) {
            int glo = __shfl(g1, 0), ghi = __shfl(g1, 15);
            if (glo == ghi) {
#pragma unroll
                for (int nt = 0; nt < 8; ++nt) {
                    float4 v = make_float4(acc1[nt][0], acc1[nt][1], acc1[nt][2], acc1[nt][3]);
#pragma unroll
                    for (int off = 1; off < 16; off <<= 1) {
                        v.x += __shfl_xor(v.x, off);
                        v.y += __shfl_xor(v.y, off);
                        v.z += __shfl_xor(v.z, off);
                        v.w += __shfl_xor(v.w, off);
                    }
                    if (m16 == 0) {
                        float* sp = &ldsH[glo * 128 + nt * 16 + quad * 4];
                        atomicAdd(sp + 0, v.x); atomicAdd(sp + 1, v.y);
                        atomicAdd(sp + 2, v.z); atomicAdd(sp + 3, v.w);
                    }
                }
            } else {
#pragma unroll
                for (int nt = 0; nt < 8; ++nt)
#pragma unroll
                    for (int i = 0; i < 4; ++i)
                        atomicAdd(&ldsH[g1 * 128 + nt * 16 + quad * 4 + i], acc1[nt][i]);
            }
        }
        // convert h' -> permuted fragments (reuse ph/pl)
#pragma unroll
        for (int k0 = 0; k0 < 4; ++k0) {
            float v[8] = {acc0[2 * k0][0], acc0[2 * k0][1], acc0[2 * k0][2], acc0[2 * k0][3],
                          acc0[2 * k0 + 1][0], acc0[2 * k0 + 1][1], acc0[2 * k0 + 1][2], acc0[2 * k0 + 1][3]};
            cvt8(v, ph0[k0], pl0[k0]);
        }
#pragma unroll
        for (int k0 = 0; k0 < 4; ++k0) {
            float v[8] = {acc1[2 * k0][0], acc1[2 * k0][1], acc1[2 * k0][2], acc1[2 * k0][3],
                          acc1[2 * k0 + 1][0], acc1[2 * k0 + 1][1], acc1[2 * k0 + 1][2], acc1[2 * k0 + 1][3]};
            cvt8(v, ph1[k0], pl1[k0]);
        }
        __syncthreads();
        {
            float* pf = partf + (size_t)blockIdx.x * 1024;
            for (int i = tid; i < 1024; i += 512) pf[i] = ldsH[i];
        }
        // Ps = h'@Wm1sp
        copyW(Wsh, Wsl);
        __syncthreads();
#pragma unroll
        for (int nt = 0; nt < 8; ++nt) { acc0[nt] = (floatx4)0.f; acc1[nt] = (floatx4)0.f; }
        mmacc(ph0, pl0, ph1, pl1);
        {
            float* d0 = Ps + (size_t)r0 * 128 + quad * 4;
#pragma unroll
            for (int nt = 0; nt < 8; ++nt)
                *(float4*)(d0 + nt * 16) = make_float4(acc0[nt][0], acc0[nt][1], acc0[nt][2], acc0[nt][3]);
            if (h1) {
                float* d1 = Ps + (size_t)r1 * 128 + quad * 4;
#pragma unroll
                for (int nt = 0; nt < 8; ++nt)
                    *(float4*)(d1 + nt * 16) = make_float4(acc1[nt][0], acc1[nt][1], acc1[nt][2], acc1[nt][3]);
            }
        }
        // Pd = h'@Wm1dp + bm1
        __syncthreads();
        copyW(Wdh, Wdl);
        __syncthreads();
#pragma unroll
        for (int nt = 0; nt < 8; ++nt) {
            float4 bv = *(const float4*)(bm1 + nt * 16 + quad * 4);
            acc0[nt][0] = bv.x; acc0[nt][1] = bv.y; acc0[nt][2] = bv.z; acc0[nt][3] = bv.w;
            acc1[nt][0] = bv.x; acc1[nt][1] = bv.y; acc1[nt][2] = bv.z; acc1[nt][3] = bv.w;
        }
        mmacc(ph0, pl0, ph1, pl1);
        {
            float* d0 = Pd + (size_t)r0 * 128 + quad * 4;
#pragma unroll
            for (int nt = 0; nt < 8; ++nt)
                *(float4*)(d0 + nt * 16) = make_float4(acc0[nt][0], acc0[nt][1], acc0[nt][2], acc0[nt][3]);
            if (h1) {
                float* d1 = Pd + (size_t)r1 * 128 + quad * 4;
#pragma unroll
                for (int nt = 0; nt < 8; ++nt)
                    *(float4*)(d1 + nt * 16) = make_float4(acc1[nt][0], acc1[nt][1], acc1[nt][2], acc1[nt][3]);
            }
        }
    } else {
        // DEC: convert h' -> permuted fragments, dec1 via Wd1p, dec2 in-register
#pragma unroll
        for (int k0 = 0; k0 < 4; ++k0) {
            float v[8] = {acc0[2 * k0][0], acc0[2 * k0][1], acc0[2 * k0][2], acc0[2 * k0][3],
                          acc0[2 * k0 + 1][0], acc0[2 * k0 + 1][1], acc0[2 * k0 + 1][2], acc0[2 * k0 + 1][3]};
            cvt8(v, ph0[k0], pl0[k0]);
        }
#pragma unroll
        for (int k0 = 0; k0 < 4; ++k0) {
            float v[8] = {acc1[2 * k0][0], acc1[2 * k0][1], acc1[2 * k0][2], acc1[2 * k0][3],
                          acc1[2 * k0 + 1][0], acc1[2 * k0 + 1][1], acc1[2 * k0 + 1][2], acc1[2 * k0 + 1][3]};
            cvt8(v, ph1[k0], pl1[k0]);
        }
        __syncthreads();
        copyW(Wdh, Wdl);   // Wd1 permuted pack
        __syncthreads();
#pragma unroll
        for (int nt = 0; nt < 8; ++nt) {
            float4 bv = *(const float4*)(bd1 + nt * 16 + quad * 4);
            acc0[nt][0] = bv.x; acc0[nt][1] = bv.y; acc0[nt][2] = bv.z; acc0[nt][3] = bv.w;
            acc1[nt][0] = bv.x; acc1[nt][1] = bv.y; acc1[nt][2] = bv.z; acc1[nt][3] = bv.w;
        }
        mmacc(ph0, pl0, ph1, pl1);
        float p00 = 0.f, p01 = 0.f, p02 = 0.f, p10 = 0.f, p11 = 0.f, p12 = 0.f;
#pragma unroll
        for (int nt = 0; nt < 8; ++nt) {
#pragma unroll
            for (int i = 0; i < 4; ++i) {
                int c = nt * 16 + quad * 4 + i;
                const float* wp = &Wd2[c * 3];
                float v0 = fmaxf(acc0[nt][i], 0.f);
                float v1 = fmaxf(acc1[nt][i], 0.f);
                p00 += v0 * wp[0]; p01 += v0 * wp[1]; p02 += v0 * wp[2];
                p10 += v1 * wp[0]; p11 += v1 * wp[1]; p12 += v1 * wp[2];
            }
        }
        p00 += __shfl_xor(p00, 16); p00 += __shfl_xor(p00, 32);
        p01 += __shfl_xor(p01, 16); p01 += __shfl_xor(p01, 32);
        p02 += __shfl_xor(p02, 16); p02 += __shfl_xor(p02, 32);
        p10 += __shfl_xor(p10, 16); p10 += __shfl_xor(p10, 32);
        p11 += __shfl_xor(p11, 16); p11 += __shfl_xor(p11, 32);
        p12 += __shfl_xor(p12, 16); p12 += __shfl_xor(p12, 32);
        if (quad == 0) {
            outp[r0 * 3 + 0] = p00 + bd2[0];
            outp[r0 * 3 + 1] = p01 + bd2[1];
            outp[r0 * 3 + 2] = p02 + bd2[2];
            if (h1) {
                outp[r1 * 3 + 0] = p10 + bd2[0];
                outp[r1 * 3 + 1] = p11 + bd2[1];
                outp[r1 * 3 + 2] = p12 + bd2[2];
            }
        }
    }
}

// ---------------- edge aggregation + gterm (merged dispatch) ----------------
// blocks [0, NN/4): one wave per destination node (edge_agg).
// blocks [NN/4, NN/4+GG): gterm for graph g = bid - NN/4.
template <int SRC>
__global__ __launch_bounds__(256) void k_edge_gterm(
    const float* __restrict__ Ps, const float* __restrict__ Pd,
    const int* __restrict__ row_ptr, const int* __restrict__ src_sorted,
    const float4* __restrict__ ea_s, const float* __restrict__ Wm1,
    float* __restrict__ accm,
    const float* __restrict__ part_a, const float* __restrict__ part_b,
    float* __restrict__ sum_hbc,
    const float* __restrict__ cnt_node, const float* __restrict__ cnt_bc,
    const float* __restrict__ Wu1, float* __restrict__ gt) {
    if (blockIdx.x >= NN / 4) {
        const int g = blockIdx.x - NN / 4;
        const int c = threadIdx.x;
        __shared__ float sg[128], sb[128];
        if (c < 128) {
            const float invn = 1.f / fmaxf(cnt_node[g], 1.f);
            const float invb = 1.f / fmaxf(cnt_bc[g], 1.f);
            float s0 = 0.f, sbv;
            if (SRC == 0) {
                float sbb = 0.f;
                for (int b = 0; b < BGRID; ++b) {
                    s0 += part_a[b * 1024 + g * 128 + c];
                    sbb += part_b[b * 1024 + g * 128 + c];
                }
                sum_hbc[g * 128 + c] = sbb;
                sbv = sbb;
            } else {
                for (int b = 0; b < BGRID; ++b) s0 += part_a[b * 1024 + g * 128 + c];
                sbv = sum_hbc[g * 128 + c];
            }
            sg[c] = s0 * invn;
            sb[c] = sbv * invb;
        }
        __syncthreads();
        if (c < 128) {
            float s = 0.f;
            for (int k = 0; k < 128; ++k) s += sg[k] * Wu1[(256 + k) * 128 + c];
            for (int k = 0; k < 128; ++k) s += sb[k] * Wu1[(384 + k) * 128 + c];
            gt[g * 128 + c] = s;
        }
        return;
    }
    const int lane = threadIdx.x & 63;
    const int d = blockIdx.x * 4 + (threadIdx.x >> 6);
    const int c = lane * 2;
    const float2 w0 = *(const float2*)&Wm1[256 * 128 + c];
    const float2 w1 = *(const float2*)&Wm1[257 * 128 + c];
    const float2 w2 = *(const float2*)&Wm1[258 * 128 + c];
    const float2 pd = *(const float2*)&Pd[(size_t)d * 128 + c];
    const int beg = row_ptr[d], end = row_ptr[d + 1];
    const float2 sv = *(const float2*)&Ps[(size_t)d * 128 + c];
    float ax = fmaxf(sv.x + pd.x, 0.f);
    float ay = fmaxf(sv.y + pd.y, 0.f);
    int k = beg;
    for (; k + 3 < end; k += 4) {
        int s0 = src_sorted[k], s1 = src_sorted[k + 1], s2 = src_sorted[k + 2], s3 = src_sorted[k + 3];
        float4 e0 = ea_s[k], e1 = ea_s[k + 1], e2 = ea_s[k + 2], e3 = ea_s[k + 3];
        float2 pa = *(const float2*)&Ps[(size_t)s0 * 128 + c];
        float2 pb = *(const float2*)&Ps[(size_t)s1 * 128 + c];
        float2 pc = *(const float2*)&Ps[(size_t)s2 * 128 + c];
        float2 pe = *(const float2*)&Ps[(size_t)s3 * 128 + c];
        ax += fmaxf(pa.x + pd.x + e0.x * w0.x + e0.y * w1.x + e0.z * w2.x, 0.f)
            + fmaxf(pb.x + pd.x + e1.x * w0.x + e1.y * w1.x + e1.z * w2.x, 0.f)
            + fmaxf(pc.x + pd.x + e2.x * w0.x + e2.y * w1.x + e2.z * w2.x, 0.f)
            + fmaxf(pe.x + pd.x + e3.x * w0.x + e3.y * w1.x + e3.z * w2.x, 0.f);
        ay += fmaxf(pa.y + pd.y + e0.x * w0.y + e0.y * w1.y + e0.z * w2.y, 0.f)
            + fmaxf(pb.y + pd.y + e1.x * w0.y + e1.y * w1.y + e1.z * w2.y, 0.f)
            + fmaxf(pc.y + pd.y + e2.x * w0.y + e2.y * w1.y + e2.z * w2.y, 0.f)
            + fmaxf(pe.y + pd.y + e3.x * w0.y + e3.y * w1.y + e3.z * w2.y, 0.f);
    }
    for (; k < end; ++k) {
        int s0 = src_sorted[k];
        float4 e0 = ea_s[k];
        float2 pa = *(const float2*)&Ps[(size_t)s0 * 128 + c];
        ax += fmaxf(pa.x + pd.x + e0.x * w0.x + e0.y * w1.x + e0.z * w2.x, 0.f);
        ay += fmaxf(pa.y + pd.y + e0.x * w0.y + e0.y * w1.y + e0.z * w2.y, 0.f);
    }
    float inv = 1.f / (float)(end - beg + 1);
    *(float2*)&accm[(size_t)d * 128 + c] = make_float2(ax * inv, ay * inv);
}

extern "C" void kernel_launch(void* const* d_in, const int* in_sizes, int n_in,
                              void* d_out, int out_size, void* d_ws, size_t ws_size,
                              hipStream_t stream) {
    const float* x = (const float*)d_in[0];
    const float* x_mask = (const float*)d_in[1];
    const float* edge_attr = (const float*)d_in[2];
    const float* W_e1 = (const float*)d_in[4];
    const float* b_e1 = (const float*)d_in[5];
    const float* W_e2 = (const float*)d_in[6];
    const float* b_e2 = (const float*)d_in[7];
    const float* W_m1 = (const float*)d_in[8];
    const float* b_m1 = (const float*)d_in[9];
    const float* W_m2 = (const float*)d_in[10];
    const float* b_m2 = (const float*)d_in[11];
    const float* W_u1 = (const float*)d_in[12];
    const float* b_u1 = (const float*)d_in[13];
    const float* W_u2 = (const float*)d_in[14];
    const float* b_u2 = (const float*)d_in[15];
    const float* W_d1 = (const float*)d_in[16];
    const float* b_d1 = (const float*)d_in[17];
    const float* W_d2 = (const float*)d_in[18];
    const float* b_d2 = (const float*)d_in[19];
    const int* edge_index = (const int*)d_in[20];
    const int* batch = (const int*)d_in[21];
    float* out = (float*)d_out;

    char* wp = (char*)d_ws;
    auto carve = [&](size_t bytes) {
        char* r = wp;
        wp += (bytes + 255) & ~(size_t)255;
        return r;
    };
    float* h = (float*)carve(sizeof(float) * (size_t)NN * 128);
    float* Ps = (float*)carve(sizeof(float) * (size_t)NN * 128);
    float* Pd = (float*)carve(sizeof(float) * (size_t)NN * 128);
    float* accm = (float*)carve(sizeof(float) * (size_t)NN * 128);
    float4* ea_s = (float4*)carve(sizeof(float4) * (size_t)EE);
    float* stats = (float*)carve(sizeof(float) * 4096);
    float* sum_hbc = stats + 1024;    // 1024
    float* cnt_node = stats + 2048;   // 8
    float* cnt_bc = stats + 2056;     // 8
    float* gterm = stats + 2304;      // 1024
    float* bfused = stats + 3328;     // 128
    float* part_h = (float*)carve(sizeof(float) * (size_t)BGRID * 1024);
    float* part_hbc = (float*)carve(sizeof(float) * (size_t)BGRID * 1024);
    float* partf = (float*)carve(sizeof(float) * (size_t)BGRID * 1024);
    int* deg = (int*)carve(sizeof(int) * NN);
    int* row_ptr = (int*)carve(sizeof(int) * (NN + 1));
    int* cursor = (int*)carve(sizeof(int) * NN);
    int* src_sorted = (int*)carve(sizeof(int) * EE);
    int* exbuf = (int*)carve(sizeof(int) * NN);
    int* blksum = (int*)carve(sizeof(int) * 256);
    float* Wf = (float*)carve(sizeof(float) * 16384);
    short* We2h = (short*)carve(sizeof(short) * 16384);
    short* We2l = (short*)carve(sizeof(short) * 16384);
    short* Wm1sh = (short*)carve(sizeof(short) * 16384);
    short* Wm1sl = (short*)carve(sizeof(short) * 16384);
    short* Wm1dh = (short*)carve(sizeof(short) * 16384);
    short* Wm1dl = (short*)carve(sizeof(short) * 16384);
    short* Wu1ah = (short*)carve(sizeof(short) * 16384);
    short* Wu1al = (short*)carve(sizeof(short) * 16384);
    short* Wfh = (short*)carve(sizeof(short) * 16384);
    short* Wfl = (short*)carve(sizeof(short) * 16384);
    short* Wu2h = (short*)carve(sizeof(short) * 16384);
    short* Wu2l = (short*)carve(sizeof(short) * 16384);
    short* Wd1h = (short*)carve(sizeof(short) * 16384);
    short* Wd1l = (short*)carve(sizeof(short) * 16384);

    const dim3 b256(256);
    const dim3 b512(512);
    const int gE256 = (EE + 255) / 256;

    hipMemsetAsync(deg, 0, sizeof(int) * NN, stream);
    hipMemsetAsync(stats, 0, sizeof(float) * 2064, stream);
    k_wfuse<<<65, b256, 0, stream>>>(W_m2, W_u1, b_m2, b_u1, Wf, bfused);
    k_pack_all<<<448, b256, 0, stream>>>(W_e2, W_m1, W_u1, Wf, W_u2, W_d1,
                                         We2h, We2l, Wm1sh, Wm1sl, Wm1dh, Wm1dl,
                                         Wu1ah, Wu1al, Wfh, Wfl, Wu2h, Wu2l, Wd1h, Wd1l);
    // CSR
    k_count<<<gE256, b256, 0, stream>>>(edge_index, deg);
    k_scan1<<<NBLK, b256, 0, stream>>>(deg, exbuf, blksum);
    k_scan2<<<1, b256, 0, stream>>>(blksum);
    k_scan3<<<NBLK, b256, 0, stream>>>(exbuf, blksum, row_ptr, cursor);
    k_scatter<<<gE256, b256, 0, stream>>>(edge_index, edge_attr, cursor, src_sorted, ea_s);
    k_counts<<<NBLK, b256, 0, stream>>>(batch, x_mask, cnt_node, cnt_bc);
    // fused encoder: h + Ps + Pd + partial stats (512-thread blocks)
    k_genc<<<BGRID, b512, 0, stream>>>(x, x_mask, W_e1, b_e1, We2h, We2l, b_e2,
                                       Wm1sh, Wm1sl, Wm1dh, Wm1dl, b_m1, batch,
                                       h, Ps, Pd, part_h, part_hbc);

    const int EGRID = NN / 4 + GG;
    for (int rep = 0; rep < 3; ++rep) {
        if (rep == 0)
            k_edge_gterm<0><<<EGRID, b256, 0, stream>>>(Ps, Pd, row_ptr, src_sorted, ea_s, W_m1, accm,
                                                        part_h, part_hbc, sum_hbc, cnt_node, cnt_bc,
                                                        W_u1, gterm);
        else
            k_edge_gterm<1><<<EGRID, b256, 0, stream>>>(Ps, Pd, row_ptr, src_sorted, ea_s, W_m1, accm,
                                                        partf, nullptr, sum_hbc, cnt_node, cnt_bc,
                                                        W_u1, gterm);
        if (rep < 2) {
            k_fused3<0><<<BGRID, b512, 0, stream>>>(h, accm, Wu1ah, Wu1al, Wfh, Wfl, Wu2h, Wu2l,
                                                    Wm1sh, Wm1sl, Wm1dh, Wm1dl,
                                                    gterm, bfused, b_u2, b_m1, nullptr, nullptr,
                                                    nullptr, batch, h, Ps, Pd, partf, nullptr);
        } else {
            k_fused3<1><<<BGRID, b512, 0, stream>>>(h, accm, Wu1ah, Wu1al, Wfh, Wfl, Wu2h, Wu2l,
                                                    nullptr, nullptr, Wd1h, Wd1l,
                                                    gterm, bfused, b_u2, nullptr, b_d1, W_d2,
                                                    b_d2, batch, nullptr, nullptr, nullptr,
                                                    nullptr, out);
        }
    }
}

// Round 12
// 581.724 us; speedup vs baseline: 1.8277x; 1.0237x over previous
//
#include <hip/hip_runtime.h>

// EPD GNN, r23. r22 (595.5us best: 512-thread genc/fused3 @ launch_bounds(512,2),
// VGPR=128 no spill) + zero-risk launch deletion:
//  - hipMemsetAsync(deg) and hipMemsetAsync(stats) absorbed into k_wfuse's grid
//    (block 64 zeros stats, blocks 65..260 zero deg; stream order covers deps).
//  - k_counts merged into k_count's grid (blocks < NBLK do node counts).
// Heavy kernels bit-identical to r22.

#define NN 50000
#define EE 400000
#define GG 8
#define NBLK 196   // ceil(NN/256)
#define BGRID 256  // 512-thread kernels: 2048 waves over 3125 tiles

typedef __attribute__((ext_vector_type(8))) short short8;
typedef __attribute__((ext_vector_type(4))) float floatx4;

__device__ __forceinline__ unsigned short f2bf(float x) {
    unsigned u = __float_as_uint(x);
    u += 0x7FFF + ((u >> 16) & 1);
    return (unsigned short)(u >> 16);
}
__device__ __forceinline__ float bf2f(unsigned short h) {
    return __uint_as_float(((unsigned)h) << 16);
}
__device__ __forceinline__ void cvt8(const float* v, short8& hi, short8& lo) {
#pragma unroll
    for (int j = 0; j < 8; ++j) {
        unsigned short h = f2bf(v[j]);
        hi[j] = (short)h;
        lo[j] = (short)f2bf(v[j] - bf2f(h));
    }
}

// ---------------- CSR count + per-graph counts (merged) ----------------
__global__ __launch_bounds__(256) void k_count(const int* __restrict__ ei, int* __restrict__ deg,
                                               const int* __restrict__ batch, const float* __restrict__ xm,
                                               float* __restrict__ cnt_node, float* __restrict__ cnt_bc) {
    int i = blockIdx.x * 256 + threadIdx.x;
    if (i < EE) atomicAdd(&deg[ei[EE + i]], 1);
    if (blockIdx.x < NBLK) {
        __shared__ float cn[8], cb[8];
        const int t = threadIdx.x;
        if (t < 8) { cn[t] = 0.f; cb[t] = 0.f; }
        __syncthreads();
        if (i < NN) {
            int g = batch[i];
            atomicAdd(&cn[g], 1.f);
            atomicAdd(&cb[g], xm[3 * i + 2]);
        }
        __syncthreads();
        if (t < 8) {
            if (cn[t] != 0.f) atomicAdd(&cnt_node[t], cn[t]);
            if (cb[t] != 0.f) atomicAdd(&cnt_bc[t], cb[t]);
        }
    }
}

__global__ __launch_bounds__(256) void k_scan1(const int* __restrict__ deg, int* __restrict__ ex,
                                               int* __restrict__ blksum) {
    __shared__ int s[256];
    const int t = threadIdx.x;
    int i = blockIdx.x * 256 + t;
    int v = (i < NN) ? deg[i] : 0;
    s[t] = v;
    __syncthreads();
    for (int off = 1; off < 256; off <<= 1) {
        int x = (t >= off) ? s[t - off] : 0;
        __syncthreads();
        s[t] += x;
        __syncthreads();
    }
    if (i < NN) ex[i] = s[t] - v;
    if (t == 255) blksum[blockIdx.x] = s[255];
}

__global__ __launch_bounds__(256) void k_scan2(int* __restrict__ blksum) {
    __shared__ int s[256];
    const int t = threadIdx.x;
    int v = (t < NBLK) ? blksum[t] : 0;
    s[t] = v;
    __syncthreads();
    for (int off = 1; off < 256; off <<= 1) {
        int x = (t >= off) ? s[t - off] : 0;
        __syncthreads();
        s[t] += x;
        __syncthreads();
    }
    if (t < NBLK) blksum[t] = s[t] - v;
}

__global__ void k_scan3(const int* __restrict__ ex, const int* __restrict__ blkoff,
                        int* __restrict__ row_ptr, int* __restrict__ cursor) {
    int i = blockIdx.x * 256 + threadIdx.x;
    if (i < NN) {
        int v = ex[i] + blkoff[blockIdx.x];
        row_ptr[i] = v;
        cursor[i] = v;
    }
    if (i == 0) row_ptr[NN] = EE;
}

__global__ void k_scatter(const int* __restrict__ ei, const float* __restrict__ ea,
                          int* __restrict__ cursor, int* __restrict__ src_sorted,
                          float4* __restrict__ ea_s) {
    int e = blockIdx.x * 256 + threadIdx.x;
    if (e >= EE) return;
    int s = ei[e], d = ei[EE + e];
    int p = atomicAdd(&cursor[d], 1);
    src_sorted[p] = s;
    ea_s[p] = make_float4(ea[3 * e], ea[3 * e + 1], ea[3 * e + 2], 0.f);
}

// ---------------- weight fusion + buffer zeroing (merged grid) ----------------
// blocks 0..63: Wf = Wm2 @ Wu1[128:256]
// block 64:     bf = bu1 + bm2 @ Wu1[128:256]; zero stats[0..2063]
// blocks 65..260: zero deg[NN]
__global__ __launch_bounds__(256) void k_wfuse(const float* __restrict__ Wm2, const float* __restrict__ Wu1,
                                               const float* __restrict__ bm2, const float* __restrict__ bu1,
                                               float* __restrict__ Wf, float* __restrict__ bf,
                                               float* __restrict__ stats, int* __restrict__ deg) {
    if (blockIdx.x > 64) {
        int i = (blockIdx.x - 65) * 256 + threadIdx.x;
        if (i < NN) deg[i] = 0;
        return;
    }
    if (blockIdx.x == 64) {
        int c = threadIdx.x;
        for (int i = c; i < 2064; i += 256) stats[i] = 0.f;
        if (c < 128) {
            float s = bu1[c];
            for (int k = 0; k < 128; ++k) s += bm2[k] * Wu1[(128 + k) * 128 + c];
            bf[c] = s;
        }
        return;
    }
    int idx = blockIdx.x * 256 + threadIdx.x;   // 16384
    int r = idx >> 7, c = idx & 127;
    float s = 0.f;
    for (int k = 0; k < 128; ++k) s += Wm2[r * 128 + k] * Wu1[(128 + k) * 128 + c];
    Wf[idx] = s;
}

// ---------------- weight packing ----------------
// normal (ids 0,3,4):  k = k0*32 + quad*8 + j
// permuted (ids 1,2,5,6): k = k0*32 + 16*(j>>2) + 4*quad + (j&3)
__global__ __launch_bounds__(256) void k_pack_all(
    const float* __restrict__ We2, const float* __restrict__ Wm1,
    const float* __restrict__ Wu1, const float* __restrict__ Wf,
    const float* __restrict__ Wu2, const float* __restrict__ Wd1,
    short* __restrict__ We2h, short* __restrict__ We2l,
    short* __restrict__ Wm1sh, short* __restrict__ Wm1sl,
    short* __restrict__ Wm1dh, short* __restrict__ Wm1dl,
    short* __restrict__ Wu1ah, short* __restrict__ Wu1al,
    short* __restrict__ Wfh, short* __restrict__ Wfl,
    short* __restrict__ Wu2h, short* __restrict__ Wu2l,
    short* __restrict__ Wd1h, short* __restrict__ Wd1l) {
    int b = blockIdx.x;
    int id = b >> 6;
    int p = (b & 63) * 256 + threadIdx.x;   // 0..16383
    const float* W;
    short *hi, *lo;
    switch (id) {
        case 0: W = We2; hi = We2h; lo = We2l; break;
        case 1: W = Wm1; hi = Wm1sh; lo = Wm1sl; break;
        case 2: W = Wm1 + 16384; hi = Wm1dh; lo = Wm1dl; break;
        case 3: W = Wu1; hi = Wu1ah; lo = Wu1al; break;
        case 4: W = Wf; hi = Wfh; lo = Wfl; break;
        case 5: W = Wu2; hi = Wu2h; lo = Wu2l; break;
        default: W = Wd1; hi = Wd1h; lo = Wd1l; break;
    }
    int j = p & 7;
    int lane = (p >> 3) & 63;
    int chunk = p >> 9;          // 0..31
    int k0 = chunk & 3, nt = chunk >> 2;
    int quad = lane >> 4;
    int n = nt * 16 + (lane & 15);
    bool perm = (id == 1) || (id == 2) || (id == 5) || (id == 6);
    int k;
    if (perm) k = k0 * 32 + ((j >> 2) << 4) + (quad << 2) + (j & 3);
    else k = k0 * 32 + quad * 8 + j;
    float w = W[k * 128 + n];
    unsigned short h = f2bf(w);
    hi[p] = (short)h;
    lo[p] = (short)f2bf(w - bf2f(h));
}

// ---------------- fused encoder (512 threads): h, Ps, Pd (+ partial stats) ----------------
__global__ __launch_bounds__(512, 2) void k_genc(
    const float* __restrict__ x, const float* __restrict__ xm,
    const float* __restrict__ We1, const float* __restrict__ be1,
    const short* __restrict__ W2h, const short* __restrict__ W2l,
    const float* __restrict__ be2,
    const short* __restrict__ Wsh, const short* __restrict__ Wsl,
    const short* __restrict__ Wdh, const short* __restrict__ Wdl,
    const float* __restrict__ bm1, const int* __restrict__ batch,
    float* __restrict__ hout, float* __restrict__ Ps, float* __restrict__ Pd,
    float* __restrict__ part_h, float* __restrict__ part_hbc) {
    __shared__ __align__(16) short sWh[16384];
    __shared__ __align__(16) short sWl[16384];
    __shared__ __align__(16) float swe[1024];   // native We1 layout [kk][c]
    __shared__ float sbe[128];
    __shared__ float ldsH[1024];
    __shared__ float ldsB[1024];
    const int tid = threadIdx.x;
    const int wave = tid >> 6, lane = tid & 63;
    const int m16 = lane & 15, quad = lane >> 4;
    const int t0 = blockIdx.x * 8 + wave;      // 0..2047
    const int t1 = t0 + BGRID * 8;             // 2048..4095
    const bool h1 = (t1 < 3125);
    const int r0 = t0 * 16 + m16;
    const int r1 = (h1 ? t1 * 16 : 0) + m16;

    auto copyW = [&](const short* gh, const short* gl) {
        const float4* sH = (const float4*)gh;
        const float4* sL = (const float4*)gl;
        float4* dH = (float4*)sWh;
        float4* dL = (float4*)sWl;
#pragma unroll
        for (int u = 0; u < 4; ++u) {
            int i = tid + u * 512;
            dH[i] = sH[i];
            dL[i] = sL[i];
        }
    };

    {
        copyW(W2h, W2l);
        for (int i = tid; i < 1024; i += 512) {
            swe[i] = We1[i];
            ldsH[i] = 0.f;
            ldsB[i] = 0.f;
        }
        if (tid < 128) sbe[tid] = be1[tid];
    }
    float in0[8], in1[8];
#pragma unroll
    for (int k = 0; k < 5; ++k) { in0[k] = x[r0 * 5 + k]; in1[k] = x[r1 * 5 + k]; }
#pragma unroll
    for (int k = 0; k < 3; ++k) { in0[5 + k] = xm[r0 * 3 + k]; in1[5 + k] = xm[r1 * 3 + k]; }
    int g0 = batch[r0], g1 = batch[r1];
    __syncthreads();
    // enc1 outputs in A-fragment slot order: c = k0*32 + quad*8 + j
    short8 ah0[4], al0[4], ah1[4], al1[4];
#pragma unroll
    for (int k0 = 0; k0 < 4; ++k0) {
        float tv[8];
#pragma unroll
        for (int j = 0; j < 8; ++j) {
            int c = k0 * 32 + quad * 8 + j;
            float s = sbe[c];
#pragma unroll
            for (int kk = 0; kk < 8; ++kk) s += in0[kk] * swe[kk * 128 + c];
            tv[j] = fmaxf(s, 0.f);
        }
        cvt8(tv, ah0[k0], al0[k0]);
    }
#pragma unroll
    for (int k0 = 0; k0 < 4; ++k0) {
        float tv[8];
#pragma unroll
        for (int j = 0; j < 8; ++j) {
            int c = k0 * 32 + quad * 8 + j;
            float s = sbe[c];
#pragma unroll
            for (int kk = 0; kk < 8; ++kk) s += in1[kk] * swe[kk * 128 + c];
            tv[j] = fmaxf(s, 0.f);
        }
        cvt8(tv, ah1[k0], al1[k0]);
    }
    const int fb = lane << 3;
    floatx4 acc0[8], acc1[8];
    auto mmacc = [&](const short8 xh0[4], const short8 xl0[4],
                     const short8 xh1[4], const short8 xl1[4]) {
#pragma unroll
        for (int k0 = 0; k0 < 4; ++k0) {
#pragma unroll
            for (int nt = 0; nt < 8; ++nt) {
                const int base = (((nt << 2) | k0) << 9) + fb;
                short8 bh = *(const short8*)&sWh[base];
                short8 bl = *(const short8*)&sWl[base];
                acc0[nt] = __builtin_amdgcn_mfma_f32_16x16x32_bf16(bh, xh0[k0], acc0[nt], 0, 0, 0);
                acc0[nt] = __builtin_amdgcn_mfma_f32_16x16x32_bf16(bl, xh0[k0], acc0[nt], 0, 0, 0);
                acc0[nt] = __builtin_amdgcn_mfma_f32_16x16x32_bf16(bh, xl0[k0], acc0[nt], 0, 0, 0);
                if (h1) {
                    acc1[nt] = __builtin_amdgcn_mfma_f32_16x16x32_bf16(bh, xh1[k0], acc1[nt], 0, 0, 0);
                    acc1[nt] = __builtin_amdgcn_mfma_f32_16x16x32_bf16(bl, xh1[k0], acc1[nt], 0, 0, 0);
                    acc1[nt] = __builtin_amdgcn_mfma_f32_16x16x32_bf16(bh, xl1[k0], acc1[nt], 0, 0, 0);
                }
            }
        }
    };

    // h = enc1@We2 + be2 (seeded)
#pragma unroll
    for (int nt = 0; nt < 8; ++nt) {
        float4 bv = *(const float4*)(be2 + nt * 16 + quad * 4);
        acc0[nt][0] = bv.x; acc0[nt][1] = bv.y; acc0[nt][2] = bv.z; acc0[nt][3] = bv.w;
        acc1[nt][0] = bv.x; acc1[nt][1] = bv.y; acc1[nt][2] = bv.z; acc1[nt][3] = bv.w;
    }
    mmacc(ah0, al0, ah1, al1);
    {
        float* d0 = hout + (size_t)r0 * 128 + quad * 4;
#pragma unroll
        for (int nt = 0; nt < 8; ++nt)
            *(float4*)(d0 + nt * 16) = make_float4(acc0[nt][0], acc0[nt][1], acc0[nt][2], acc0[nt][3]);
    }
    if (h1) {
        float* d1 = hout + (size_t)r1 * 128 + quad * 4;
#pragma unroll
        for (int nt = 0; nt < 8; ++nt)
            *(float4*)(d1 + nt * 16) = make_float4(acc1[nt][0], acc1[nt][1], acc1[nt][2], acc1[nt][3]);
    }
    // stats -> LDS accumulators
    {
        float bc = in0[7];
        int glo = __shfl(g0, 0), ghi = __shfl(g0, 15);
        if (glo == ghi) {
#pragma unroll
            for (int nt = 0; nt < 8; ++nt) {
                float4 v = make_float4(acc0[nt][0], acc0[nt][1], acc0[nt][2], acc0[nt][3]);
                float4 w = make_float4(v.x * bc, v.y * bc, v.z * bc, v.w * bc);
#pragma unroll
                for (int off = 1; off < 16; off <<= 1) {
                    v.x += __shfl_xor(v.x, off); v.y += __shfl_xor(v.y, off);
                    v.z += __shfl_xor(v.z, off); v.w += __shfl_xor(v.w, off);
                    w.x += __shfl_xor(w.x, off); w.y += __shfl_xor(w.y, off);
                    w.z += __shfl_xor(w.z, off); w.w += __shfl_xor(w.w, off);
                }
                if (m16 == 0) {
                    float* sp = &ldsH[glo * 128 + nt * 16 + quad * 4];
                    atomicAdd(sp + 0, v.x); atomicAdd(sp + 1, v.y);
                    atomicAdd(sp + 2, v.z); atomicAdd(sp + 3, v.w);
                    float* sq = &ldsB[glo * 128 + nt * 16 + quad * 4];
                    atomicAdd(sq + 0, w.x); atomicAdd(sq + 1, w.y);
                    atomicAdd(sq + 2, w.z); atomicAdd(sq + 3, w.w);
                }
            }
        } else {
#pragma unroll
            for (int nt = 0; nt < 8; ++nt)
#pragma unroll
                for (int i = 0; i < 4; ++i) {
                    atomicAdd(&ldsH[g0 * 128 + nt * 16 + quad * 4 + i], acc0[nt][i]);
                    atomicAdd(&ldsB[g0 * 128 + nt * 16 + quad * 4 + i], acc0[nt][i] * bc);
                }
        }
    }
    if (h1) {
        float bc = in1[7];
        int glo = __shfl(g1, 0), ghi = __shfl(g1, 15);
        if (glo == ghi) {
#pragma unroll
            for (int nt = 0; nt < 8; ++nt) {
                float4 v = make_float4(acc1[nt][0], acc1[nt][1], acc1[nt][2], acc1[nt][3]);
                float4 w = make_float4(v.x * bc, v.y * bc, v.z * bc, v.w * bc);
#pragma unroll
                for (int off = 1; off < 16; off <<= 1) {
                    v.x += __shfl_xor(v.x, off); v.y += __shfl_xor(v.y, off);
                    v.z += __shfl_xor(v.z, off); v.w += __shfl_xor(v.w, off);
                    w.x += __shfl_xor(w.x, off); w.y += __shfl_xor(w.y, off);
                    w.z += __shfl_xor(w.z, off); w.w += __shfl_xor(w.w, off);
                }
                if (m16 == 0) {
                    float* sp = &ldsH[glo * 128 + nt * 16 + quad * 4];
                    atomicAdd(sp + 0, v.x); atomicAdd(sp + 1, v.y);
                    atomicAdd(sp + 2, v.z); atomicAdd(sp + 3, v.w);
                    float* sq = &ldsB[glo * 128 + nt * 16 + quad * 4];
                    atomicAdd(sq + 0, w.x); atomicAdd(sq + 1, w.y);
                    atomicAdd(sq + 2, w.z); atomicAdd(sq + 3, w.w);
                }
            }
        } else {
#pragma unroll
            for (int nt = 0; nt < 8; ++nt)
#pragma unroll
                for (int i = 0; i < 4; ++i) {
                    atomicAdd(&ldsH[g1 * 128 + nt * 16 + quad * 4 + i], acc1[nt][i]);
                    atomicAdd(&ldsB[g1 * 128 + nt * 16 + quad * 4 + i], acc1[nt][i] * bc);
                }
        }
    }
    // convert in-register h -> permuted A-fragments
    short8 ph0[4], pl0[4], ph1[4], pl1[4];
#pragma unroll
    for (int k0 = 0; k0 < 4; ++k0) {
        float v[8] = {acc0[2 * k0][0], acc0[2 * k0][1], acc0[2 * k0][2], acc0[2 * k0][3],
                      acc0[2 * k0 + 1][0], acc0[2 * k0 + 1][1], acc0[2 * k0 + 1][2], acc0[2 * k0 + 1][3]};
        cvt8(v, ph0[k0], pl0[k0]);
    }
#pragma unroll
    for (int k0 = 0; k0 < 4; ++k0) {
        float v[8] = {acc1[2 * k0][0], acc1[2 * k0][1], acc1[2 * k0][2], acc1[2 * k0][3],
                      acc1[2 * k0 + 1][0], acc1[2 * k0 + 1][1], acc1[2 * k0 + 1][2], acc1[2 * k0 + 1][3]};
        cvt8(v, ph1[k0], pl1[k0]);
    }
    __syncthreads();
    // dense per-block partial store (after sync: all LDS atomics landed)
    {
        float* ph = part_h + (size_t)blockIdx.x * 1024;
        float* pb = part_hbc + (size_t)blockIdx.x * 1024;
        for (int i = tid; i < 1024; i += 512) { ph[i] = ldsH[i]; pb[i] = ldsB[i]; }
    }
    // Ps = h@Wm1sp
    copyW(Wsh, Wsl);
    __syncthreads();
#pragma unroll
    for (int nt = 0; nt < 8; ++nt) { acc0[nt] = (floatx4)0.f; acc1[nt] = (floatx4)0.f; }
    mmacc(ph0, pl0, ph1, pl1);
    {
        float* d0 = Ps + (size_t)r0 * 128 + quad * 4;
#pragma unroll
        for (int nt = 0; nt < 8; ++nt)
            *(float4*)(d0 + nt * 16) = make_float4(acc0[nt][0], acc0[nt][1], acc0[nt][2], acc0[nt][3]);
        if (h1) {
            float* d1 = Ps + (size_t)r1 * 128 + quad * 4;
#pragma unroll
            for (int nt = 0; nt < 8; ++nt)
                *(float4*)(d1 + nt * 16) = make_float4(acc1[nt][0], acc1[nt][1], acc1[nt][2], acc1[nt][3]);
        }
    }
    // Pd = h@Wm1dp + bm1 (seeded)
    __syncthreads();
    copyW(Wdh, Wdl);
    __syncthreads();
#pragma unroll
    for (int nt = 0; nt < 8; ++nt) {
        float4 bv = *(const float4*)(bm1 + nt * 16 + quad * 4);
        acc0[nt][0] = bv.x; acc0[nt][1] = bv.y; acc0[nt][2] = bv.z; acc0[nt][3] = bv.w;
        acc1[nt][0] = bv.x; acc1[nt][1] = bv.y; acc1[nt][2] = bv.z; acc1[nt][3] = bv.w;
    }
    mmacc(ph0, pl0, ph1, pl1);
    {
        float* d0 = Pd + (size_t)r0 * 128 + quad * 4;
#pragma unroll
        for (int nt = 0; nt < 8; ++nt)
            *(float4*)(d0 + nt * 16) = make_float4(acc0[nt][0], acc0[nt][1], acc0[nt][2], acc0[nt][3]);
        if (h1) {
            float* d1 = Pd + (size_t)r1 * 128 + quad * 4;
#pragma unroll
            for (int nt = 0; nt < 8; ++nt)
                *(float4*)(d1 + nt * 16) = make_float4(acc1[nt][0], acc1[nt][1], acc1[nt][2], acc1[nt][3]);
        }
    }
}

// ---------------- FUSED3 (512 threads, 2-tile): tmp=h@Wu1a+gt+bf ; pre=relu(tmp+accm@Wf) ; h'=h+pre@Wu2p ;
// MODE 0 (EMIT): store h', stats->partf, Ps=h'@Wm1sp, Pd=h'@Wm1dp+bm1
// MODE 1 (DEC):  out = relu(h'@Wd1p + bd1) @ Wd2 + bd2   (h' never stored)
template <int MODE>
__global__ __launch_bounds__(512, 2) void k_fused3(
    const float* __restrict__ hbuf, const float* __restrict__ accm,
    const short* __restrict__ W1h, const short* __restrict__ W1l,
    const short* __restrict__ W2h, const short* __restrict__ W2l,
    const short* __restrict__ W3h, const short* __restrict__ W3l,
    const short* __restrict__ Wsh, const short* __restrict__ Wsl,
    const short* __restrict__ Wdh, const short* __restrict__ Wdl,
    const float* __restrict__ gt, const float* __restrict__ bf3,
    const float* __restrict__ bu2, const float* __restrict__ bm1,
    const float* __restrict__ bd1, const float* __restrict__ Wd2,
    const float* __restrict__ bd2, const int* __restrict__ batch,
    float* __restrict__ hout, float* __restrict__ Ps, float* __restrict__ Pd,
    float* __restrict__ partf, float* __restrict__ outp) {
    __shared__ __align__(16) short sWh[16384];
    __shared__ __align__(16) short sWl[16384];
    __shared__ float ldsH[1024];
    const int tid = threadIdx.x;
    const int wave = tid >> 6, lane = tid & 63;
    const int m16 = lane & 15, quad = lane >> 4;
    const int t0 = blockIdx.x * 8 + wave;
    const int t1 = t0 + BGRID * 8;
    const bool h1 = (t1 < 3125);
    const int r0 = t0 * 16 + m16;
    const int r1 = (h1 ? t1 * 16 : 0) + m16;

    auto copyW = [&](const short* gh, const short* gl) {
        const float4* sH = (const float4*)gh;
        const float4* sL = (const float4*)gl;
        float4* dH = (float4*)sWh;
        float4* dL = (float4*)sWl;
#pragma unroll
        for (int u = 0; u < 4; ++u) {
            int i = tid + u * 512;
            dH[i] = sH[i];
            dL[i] = sL[i];
        }
    };

    const float* Ap0 = hbuf + (size_t)r0 * 128 + quad * 8;
    const float* Ap1 = hbuf + (size_t)r1 * 128 + quad * 8;
    float4 a0[8], a1[8];
#pragma unroll
    for (int k0 = 0; k0 < 4; ++k0) {
        a0[k0 * 2 + 0] = *(const float4*)(Ap0 + k0 * 32);
        a0[k0 * 2 + 1] = *(const float4*)(Ap0 + k0 * 32 + 4);
        a1[k0 * 2 + 0] = *(const float4*)(Ap1 + k0 * 32);
        a1[k0 * 2 + 1] = *(const float4*)(Ap1 + k0 * 32 + 4);
    }
    int g0 = batch[r0], g1 = batch[r1];
    if (MODE == 0) {
        for (int i = tid; i < 1024; i += 512) ldsH[i] = 0.f;
    }
    copyW(W1h, W1l);
    __syncthreads();

    short8 hh0[4], hl0[4], hh1[4], hl1[4];
#pragma unroll
    for (int k0 = 0; k0 < 4; ++k0) {
        float v[8] = {a0[k0 * 2].x, a0[k0 * 2].y, a0[k0 * 2].z, a0[k0 * 2].w,
                      a0[k0 * 2 + 1].x, a0[k0 * 2 + 1].y, a0[k0 * 2 + 1].z, a0[k0 * 2 + 1].w};
        cvt8(v, hh0[k0], hl0[k0]);
    }
#pragma unroll
    for (int k0 = 0; k0 < 4; ++k0) {
        float v[8] = {a1[k0 * 2].x, a1[k0 * 2].y, a1[k0 * 2].z, a1[k0 * 2].w,
                      a1[k0 * 2 + 1].x, a1[k0 * 2 + 1].y, a1[k0 * 2 + 1].z, a1[k0 * 2 + 1].w};
        cvt8(v, hh1[k0], hl1[k0]);
    }

    const int fb = lane << 3;
    floatx4 acc0[8], acc1[8];
    auto mmacc = [&](const short8 xh0[4], const short8 xl0[4],
                     const short8 xh1[4], const short8 xl1[4]) {
#pragma unroll
        for (int k0 = 0; k0 < 4; ++k0) {
#pragma unroll
            for (int nt = 0; nt < 8; ++nt) {
                const int base = (((nt << 2) | k0) << 9) + fb;
                short8 bh = *(const short8*)&sWh[base];
                short8 bl = *(const short8*)&sWl[base];
                acc0[nt] = __builtin_amdgcn_mfma_f32_16x16x32_bf16(bh, xh0[k0], acc0[nt], 0, 0, 0);
                acc0[nt] = __builtin_amdgcn_mfma_f32_16x16x32_bf16(bl, xh0[k0], acc0[nt], 0, 0, 0);
                acc0[nt] = __builtin_amdgcn_mfma_f32_16x16x32_bf16(bh, xl0[k0], acc0[nt], 0, 0, 0);
                if (h1) {
                    acc1[nt] = __builtin_amdgcn_mfma_f32_16x16x32_bf16(bh, xh1[k0], acc1[nt], 0, 0, 0);
                    acc1[nt] = __builtin_amdgcn_mfma_f32_16x16x32_bf16(bl, xh1[k0], acc1[nt], 0, 0, 0);
                    acc1[nt] = __builtin_amdgcn_mfma_f32_16x16x32_bf16(bh, xl1[k0], acc1[nt], 0, 0, 0);
                }
            }
        }
    };

    // gemm1: acc = bf + gt[g] + h@Wu1a  -> tmp
    {
        const float* gp0 = gt + g0 * 128 + quad * 4;
        const float* gp1 = gt + g1 * 128 + quad * 4;
#pragma unroll
        for (int nt = 0; nt < 8; ++nt) {
            float4 bv = *(const float4*)(bf3 + nt * 16 + quad * 4);
            float4 gv0 = *(const float4*)(gp0 + nt * 16);
            float4 gv1 = *(const float4*)(gp1 + nt * 16);
            acc0[nt][0] = bv.x + gv0.x; acc0[nt][1] = bv.y + gv0.y;
            acc0[nt][2] = bv.z + gv0.z; acc0[nt][3] = bv.w + gv0.w;
            acc1[nt][0] = bv.x + gv1.x; acc1[nt][1] = bv.y + gv1.y;
            acc1[nt][2] = bv.z + gv1.z; acc1[nt][3] = bv.w + gv1.w;
        }
    }
    mmacc(hh0, hl0, hh1, hl1);

    // accm loads (latency hides under W2 stage + sync)
    const float* Cp0 = accm + (size_t)r0 * 128 + quad * 8;
    const float* Cp1 = accm + (size_t)r1 * 128 + quad * 8;
    float4 c0[8], c1[8];
#pragma unroll
    for (int k0 = 0; k0 < 4; ++k0) {
        c0[k0 * 2 + 0] = *(const float4*)(Cp0 + k0 * 32);
        c0[k0 * 2 + 1] = *(const float4*)(Cp0 + k0 * 32 + 4);
        c1[k0 * 2 + 0] = *(const float4*)(Cp1 + k0 * 32);
        c1[k0 * 2 + 1] = *(const float4*)(Cp1 + k0 * 32 + 4);
    }
    __syncthreads();
    copyW(W2h, W2l);
    __syncthreads();

    short8 ch0[4], cl0[4], ch1[4], cl1[4];
#pragma unroll
    for (int k0 = 0; k0 < 4; ++k0) {
        float v[8] = {c0[k0 * 2].x, c0[k0 * 2].y, c0[k0 * 2].z, c0[k0 * 2].w,
                      c0[k0 * 2 + 1].x, c0[k0 * 2 + 1].y, c0[k0 * 2 + 1].z, c0[k0 * 2 + 1].w};
        cvt8(v, ch0[k0], cl0[k0]);
    }
#pragma unroll
    for (int k0 = 0; k0 < 4; ++k0) {
        float v[8] = {c1[k0 * 2].x, c1[k0 * 2].y, c1[k0 * 2].z, c1[k0 * 2].w,
                      c1[k0 * 2 + 1].x, c1[k0 * 2 + 1].y, c1[k0 * 2 + 1].z, c1[k0 * 2 + 1].w};
        cvt8(v, ch1[k0], cl1[k0]);
    }
    // gemm2: acc += accm@Wf -> pre = relu(acc)
    mmacc(ch0, cl0, ch1, cl1);

    short8 ph0[4], pl0[4], ph1[4], pl1[4];
#pragma unroll
    for (int k0 = 0; k0 < 4; ++k0) {
        float v[8] = {fmaxf(acc0[2 * k0][0], 0.f), fmaxf(acc0[2 * k0][1], 0.f),
                      fmaxf(acc0[2 * k0][2], 0.f), fmaxf(acc0[2 * k0][3], 0.f),
                      fmaxf(acc0[2 * k0 + 1][0], 0.f), fmaxf(acc0[2 * k0 + 1][1], 0.f),
                      fmaxf(acc0[2 * k0 + 1][2], 0.f), fmaxf(acc0[2 * k0 + 1][3], 0.f)};
        cvt8(v, ph0[k0], pl0[k0]);
    }
#pragma unroll
    for (int k0 = 0; k0 < 4; ++k0) {
        float v[8] = {fmaxf(acc1[2 * k0][0], 0.f), fmaxf(acc1[2 * k0][1], 0.f),
                      fmaxf(acc1[2 * k0][2], 0.f), fmaxf(acc1[2 * k0][3], 0.f),
                      fmaxf(acc1[2 * k0 + 1][0], 0.f), fmaxf(acc1[2 * k0 + 1][1], 0.f),
                      fmaxf(acc1[2 * k0 + 1][2], 0.f), fmaxf(acc1[2 * k0 + 1][3], 0.f)};
        cvt8(v, ph1[k0], pl1[k0]);
    }

    // re-seed acc = h + bu2 (epilogue layout, memory re-read)
    {
        const float* Ep0 = hbuf + (size_t)r0 * 128 + quad * 4;
        const float* Ep1 = hbuf + (size_t)r1 * 128 + quad * 4;
#pragma unroll
        for (int nt = 0; nt < 8; ++nt) {
            float4 bv = *(const float4*)(bu2 + nt * 16 + quad * 4);
            float4 e0 = *(const float4*)(Ep0 + nt * 16);
            float4 e1 = *(const float4*)(Ep1 + nt * 16);
            acc0[nt][0] = e0.x + bv.x; acc0[nt][1] = e0.y + bv.y;
            acc0[nt][2] = e0.z + bv.z; acc0[nt][3] = e0.w + bv.w;
            acc1[nt][0] = e1.x + bv.x; acc1[nt][1] = e1.y + bv.y;
            acc1[nt][2] = e1.z + bv.z; acc1[nt][3] = e1.w + bv.w;
        }
    }
    __syncthreads();
    copyW(W3h, W3l);
    __syncthreads();
    // gemm3: acc += pre@Wu2p -> h'
    mmacc(ph0, pl0, ph1, pl1);

    if (MODE == 0) {
        // store h'
        {
            float* d0 = hout + (size_t)r0 * 128 + quad * 4;
#pragma unroll
            for (int nt = 0; nt < 8; ++nt)
                *(float4*)(d0 + nt * 16) = make_float4(acc0[nt][0], acc0[nt][1], acc0[nt][2], acc0[nt][3]);
        }
        if (h1) {
            float* d1 = hout + (size_t)r1 * 128 + quad * 4;
#pragma unroll
            for (int nt = 0; nt < 8; ++nt)
                *(float4*)(d1 + nt * 16) = make_float4(acc1[nt][0], acc1[nt][1], acc1[nt][2], acc1[nt][3]);
        }
        // stats
        {
            int glo = __shfl(g0, 0), ghi = __shfl(g0, 15);
            if (glo == ghi) {
#pragma unroll
                for (int nt = 0; nt < 8; ++nt) {
                    float4 v = make_float4(acc0[nt][0], acc0[nt][1], acc0[nt][2], acc0[nt][3]);
#pragma unroll
                    for (int off = 1; off < 16; off <<= 1) {
                        v.x += __shfl_xor(v.x, off);
                        v.y += __shfl_xor(v.y, off);
                        v.z += __shfl_xor(v.z, off);
                        v.w += __shfl_xor(v.w, off);
                    }
                    if (m16 == 0) {
                        float* sp = &ldsH[glo * 128 + nt * 16 + quad * 4];
                        atomicAdd(sp + 0, v.x); atomicAdd(sp + 1, v.y);
                        atomicAdd(sp + 2, v.z); atomicAdd(sp + 3, v.w);
                    }
                }
            } else {
#pragma unroll
                for (int nt = 0; nt < 8; ++nt)
#pragma unroll
                    for (int i = 0; i < 4; ++i)
                        atomicAdd(&ldsH[g0 * 128 + nt * 16 + quad * 4 + i], acc0[nt][i]);
            }
        }
        if (h1) {
            int glo = __shfl(g1, 0), ghi = __shfl(g1, 15);
            if (glo == ghi) {
#pragma unroll
                for (int nt = 0; nt < 8; ++nt) {
                    float4 v = make_float4(acc1[nt][0], acc1[nt][1], acc1[nt][2], acc1[nt][3]);
#pragma unroll
                    for (int off = 1; off < 16; off <<= 1) {
                        v.x += __shfl_xor(v.x, off);
                        v.y += __shfl_xor(v.y, off);
                        v.z += __shfl_xor(v.z, off);
                        v.w += __shfl_xor(v.w, off);
                    }
                    if (m16 == 0) {
                        float* sp = &ldsH[glo * 128 + nt * 16 + quad * 4];
                        atomicAdd(sp + 0, v.x); atomicAdd(sp + 1, v.y);
                        atomicAdd(sp + 2, v.z); atomicAdd(sp + 3, v.w);
                    }
                }
            } else {
#pragma unroll
                for (int nt = 0; nt < 8; ++nt)
#pragma unroll
                    for (int i = 0; i < 4; ++i)
                        atomicAdd(&ldsH[g1 * 128 + nt * 16 + quad * 4 + i], acc1[nt][i]);
            }
        }
        // convert h' -> permuted fragments (reuse ph/pl)
#pragma unroll
        for (int k0 = 0; k0 < 4; ++k0) {
            float v[8] = {acc0[2 * k0][0], acc0[2 * k0][1], acc0[2 * k0][2], acc0[2 * k0][3],
                          acc0[2 * k0 + 1][0], acc0[2 * k0 + 1][1], acc0[2 * k0 + 1][2], acc0[2 * k0 + 1][3]};
            cvt8(v, ph0[k0], pl0[k0]);
        }
#pragma unroll
        for (int k0 = 0; k0 < 4; ++k0) {
            float v[8] = {acc1[2 * k0][0], acc1[2 * k0][1], acc1[2 * k0][2], acc1[2 * k0][3],
                          acc1[2 * k0 + 1][0], acc1[2 * k0 + 1][1], acc1[2 * k0 + 1][2], acc1[2 * k0 + 1][3]};
            cvt8(v, ph1[k0], pl1[k0]);
        }
        __syncthreads();
        {
            float* pf = partf + (size_t)blockIdx.x * 1024;
            for (int i = tid; i < 1024; i += 512) pf[i] = ldsH[i];
        }
        // Ps = h'@Wm1sp
        copyW(Wsh, Wsl);
        __syncthreads();
#pragma unroll
        for (int nt = 0; nt < 8; ++nt) { acc0[nt] = (floatx4)0.f; acc1[nt] = (floatx4)0.f; }
        mmacc(ph0, pl0, ph1, pl1);
        {
            float* d0 = Ps + (size_t)r0 * 128 + quad * 4;
#pragma unroll
            for (int nt = 0; nt < 8; ++nt)
                *(float4*)(d0 + nt * 16) = make_float4(acc0[nt][0], acc0[nt][1], acc0[nt][2], acc0[nt][3]);
            if (h1) {
                float* d1 = Ps + (size_t)r1 * 128 + quad * 4;
#pragma unroll
                for (int nt = 0; nt < 8; ++nt)
                    *(float4*)(d1 + nt * 16) = make_float4(acc1[nt][0], acc1[nt][1], acc1[nt][2], acc1[nt][3]);
            }
        }
        // Pd = h'@Wm1dp + bm1
        __syncthreads();
        copyW(Wdh, Wdl);
        __syncthreads();
#pragma unroll
        for (int nt = 0; nt < 8; ++nt) {
            float4 bv = *(const float4*)(bm1 + nt * 16 + quad * 4);
            acc0[nt][0] = bv.x; acc0[nt][1] = bv.y; acc0[nt][2] = bv.z; acc0[nt][3] = bv.w;
            acc1[nt][0] = bv.x; acc1[nt][1] = bv.y; acc1[nt][2] = bv.z; acc1[nt][3] = bv.w;
        }
        mmacc(ph0, pl0, ph1, pl1);
        {
            float* d0 = Pd + (size_t)r0 * 128 + quad * 4;
#pragma unroll
            for (int nt = 0; nt < 8; ++nt)
                *(float4*)(d0 + nt * 16) = make_float4(acc0[nt][0], acc0[nt][1], acc0[nt][2], acc0[nt][3]);
            if (h1) {
                float* d1 = Pd + (size_t)r1 * 128 + quad * 4;
#pragma unroll
                for (int nt = 0; nt < 8; ++nt)
                    *(float4*)(d1 + nt * 16) = make_float4(acc1[nt][0], acc1[nt][1], acc1[nt][2], acc1[nt][3]);
            }
        }
    } else {
        // DEC: convert h' -> permuted fragments, dec1 via Wd1p, dec2 in-register
#pragma unroll
        for (int k0 = 0; k0 < 4; ++k0) {
            float v[8] = {acc0[2 * k0][0], acc0[2 * k0][1], acc0[2 * k0][2], acc0[2 * k0][3],
                          acc0[2 * k0 + 1][0], acc0[2 * k0 + 1][1], acc0[2 * k0 + 1][2], acc0[2 * k0 + 1][3]};
            cvt8(v, ph0[k0], pl0[k0]);
        }
#pragma unroll
        for (int k0 = 0; k0 < 4; ++k0) {
            float v[8] = {acc1[2 * k0][0], acc1[2 * k0][1], acc1[2 * k0][2], acc1[2 * k0][3],
                          acc1[2 * k0 + 1][0], acc1[2 * k0 + 1][1], acc1[2 * k0 + 1][2], acc1[2 * k0 + 1][3]};
            cvt8(v, ph1[k0], pl1[k0]);
        }
        __syncthreads();
        copyW(Wdh, Wdl);   // Wd1 permuted pack
        __syncthreads();
#pragma unroll
        for (int nt = 0; nt < 8; ++nt) {
            float4 bv = *(const float4*)(bd1 + nt * 16 + quad * 4);
            acc0[nt][0] = bv.x; acc0[nt][1] = bv.y; acc0[nt][2] = bv.z; acc0[nt][3] = bv.w;
            acc1[nt][0] = bv.x; acc1[nt][1] = bv.y; acc1[nt][2] = bv.z; acc1[nt][3] = bv.w;
        }
        mmacc(ph0, pl0, ph1, pl1);
        float p00 = 0.f, p01 = 0.f, p02 = 0.f, p10 = 0.f, p11 = 0.f, p12 = 0.f;
#pragma unroll
        for (int nt = 0; nt < 8; ++nt) {
#pragma unroll
            for (int i = 0; i < 4; ++i) {
                int c = nt * 16 + quad * 4 + i;
                const float* wp = &Wd2[c * 3];
                float v0 = fmaxf(acc0[nt][i], 0.f);
                float v1 = fmaxf(acc1[nt][i], 0.f);
                p00 += v0 * wp[0]; p01 += v0 * wp[1]; p02 += v0 * wp[2];
                p10 += v1 * wp[0]; p11 += v1 * wp[1]; p12 += v1 * wp[2];
            }
        }
        p00 += __shfl_xor(p00, 16); p00 += __shfl_xor(p00, 32);
        p01 += __shfl_xor(p01, 16); p01 += __shfl_xor(p01, 32);
        p02 += __shfl_xor(p02, 16); p02 += __shfl_xor(p02, 32);
        p10 += __shfl_xor(p10, 16); p10 += __shfl_xor(p10, 32);
        p11 += __shfl_xor(p11, 16); p11 += __shfl_xor(p11, 32);
        p12 += __shfl_xor(p12, 16); p12 += __shfl_xor(p12, 32);
        if (quad == 0) {
            outp[r0 * 3 + 0] = p00 + bd2[0];
            outp[r0 * 3 + 1] = p01 + bd2[1];
            outp[r0 * 3 + 2] = p02 + bd2[2];
            if (h1) {
                outp[r1 * 3 + 0] = p10 + bd2[0];
                outp[r1 * 3 + 1] = p11 + bd2[1];
                outp[r1 * 3 + 2] = p12 + bd2[2];
            }
        }
    }
}

// ---------------- edge aggregation + gterm (merged dispatch) ----------------
// blocks [0, NN/4): one wave per destination node (edge_agg).
// blocks [NN/4, NN/4+GG): gterm for graph g = bid - NN/4.
template <int SRC>
__global__ __launch_bounds__(256) void k_edge_gterm(
    const float* __restrict__ Ps, const float* __restrict__ Pd,
    const int* __restrict__ row_ptr, const int* __restrict__ src_sorted,
    const float4* __restrict__ ea_s, const float* __restrict__ Wm1,
    float* __restrict__ accm,
    const float* __restrict__ part_a, const float* __restrict__ part_b,
    float* __restrict__ sum_hbc,
    const float* __restrict__ cnt_node, const float* __restrict__ cnt_bc,
    const float* __restrict__ Wu1, float* __restrict__ gt) {
    if (blockIdx.x >= NN / 4) {
        const int g = blockIdx.x - NN / 4;
        const int c = threadIdx.x;
        __shared__ float sg[128], sb[128];
        if (c < 128) {
            const float invn = 1.f / fmaxf(cnt_node[g], 1.f);
            const float invb = 1.f / fmaxf(cnt_bc[g], 1.f);
            float s0 = 0.f, sbv;
            if (SRC == 0) {
                float sbb = 0.f;
                for (int b = 0; b < BGRID; ++b) {
                    s0 += part_a[b * 1024 + g * 128 + c];
                    sbb += part_b[b * 1024 + g * 128 + c];
                }
                sum_hbc[g * 128 + c] = sbb;
                sbv = sbb;
            } else {
                for (int b = 0; b < BGRID; ++b) s0 += part_a[b * 1024 + g * 128 + c];
                sbv = sum_hbc[g * 128 + c];
            }
            sg[c] = s0 * invn;
            sb[c] = sbv * invb;
        }
        __syncthreads();
        if (c < 128) {
            float s = 0.f;
            for (int k = 0; k < 128; ++k) s += sg[k] * Wu1[(256 + k) * 128 + c];
            for (int k = 0; k < 128; ++k) s += sb[k] * Wu1[(384 + k) * 128 + c];
            gt[g * 128 + c] = s;
        }
        return;
    }
    const int lane = threadIdx.x & 63;
    const int d = blockIdx.x * 4 + (threadIdx.x >> 6);
    const int c = lane * 2;
    const float2 w0 = *(const float2*)&Wm1[256 * 128 + c];
    const float2 w1 = *(const float2*)&Wm1[257 * 128 + c];
    const float2 w2 = *(const float2*)&Wm1[258 * 128 + c];
    const float2 pd = *(const float2*)&Pd[(size_t)d * 128 + c];
    const int beg = row_ptr[d], end = row_ptr[d + 1];
    const float2 sv = *(const float2*)&Ps[(size_t)d * 128 + c];
    float ax = fmaxf(sv.x + pd.x, 0.f);
    float ay = fmaxf(sv.y + pd.y, 0.f);
    int k = beg;
    for (; k + 3 < end; k += 4) {
        int s0 = src_sorted[k], s1 = src_sorted[k + 1], s2 = src_sorted[k + 2], s3 = src_sorted[k + 3];
        float4 e0 = ea_s[k], e1 = ea_s[k + 1], e2 = ea_s[k + 2], e3 = ea_s[k + 3];
        float2 pa = *(const float2*)&Ps[(size_t)s0 * 128 + c];
        float2 pb = *(const float2*)&Ps[(size_t)s1 * 128 + c];
        float2 pc = *(const float2*)&Ps[(size_t)s2 * 128 + c];
        float2 pe = *(const float2*)&Ps[(size_t)s3 * 128 + c];
        ax += fmaxf(pa.x + pd.x + e0.x * w0.x + e0.y * w1.x + e0.z * w2.x, 0.f)
            + fmaxf(pb.x + pd.x + e1.x * w0.x + e1.y * w1.x + e1.z * w2.x, 0.f)
            + fmaxf(pc.x + pd.x + e2.x * w0.x + e2.y * w1.x + e2.z * w2.x, 0.f)
            + fmaxf(pe.x + pd.x + e3.x * w0.x + e3.y * w1.x + e3.z * w2.x, 0.f);
        ay += fmaxf(pa.y + pd.y + e0.x * w0.y + e0.y * w1.y + e0.z * w2.y, 0.f)
            + fmaxf(pb.y + pd.y + e1.x * w0.y + e1.y * w1.y + e1.z * w2.y, 0.f)
            + fmaxf(pc.y + pd.y + e2.x * w0.y + e2.y * w1.y + e2.z * w2.y, 0.f)
            + fmaxf(pe.y + pd.y + e3.x * w0.y + e3.y * w1.y + e3.z * w2.y, 0.f);
    }
    for (; k < end; ++k) {
        int s0 = src_sorted[k];
        float4 e0 = ea_s[k];
        float2 pa = *(const float2*)&Ps[(size_t)s0 * 128 + c];
        ax += fmaxf(pa.x + pd.x + e0.x * w0.x + e0.y * w1.x + e0.z * w2.x, 0.f);
        ay += fmaxf(pa.y + pd.y + e0.x * w0.y + e0.y * w1.y + e0.z * w2.y, 0.f);
    }
    float inv = 1.f / (float)(end - beg + 1);
    *(float2*)&accm[(size_t)d * 128 + c] = make_float2(ax * inv, ay * inv);
}

extern "C" void kernel_launch(void* const* d_in, const int* in_sizes, int n_in,
                              void* d_out, int out_size, void* d_ws, size_t ws_size,
                              hipStream_t stream) {
    const float* x = (const float*)d_in[0];
    const float* x_mask = (const float*)d_in[1];
    const float* edge_attr = (const float*)d_in[2];
    const float* W_e1 = (const float*)d_in[4];
    const float* b_e1 = (const float*)d_in[5];
    const float* W_e2 = (const float*)d_in[6];
    const float* b_e2 = (const float*)d_in[7];
    const float* W_m1 = (const float*)d_in[8];
    const float* b_m1 = (const float*)d_in[9];
    const float* W_m2 = (const float*)d_in[10];
    const float* b_m2 = (const float*)d_in[11];
    const float* W_u1 = (const float*)d_in[12];
    const float* b_u1 = (const float*)d_in[13];
    const float* W_u2 = (const float*)d_in[14];
    const float* b_u2 = (const float*)d_in[15];
    const float* W_d1 = (const float*)d_in[16];
    const float* b_d1 = (const float*)d_in[17];
    const float* W_d2 = (const float*)d_in[18];
    const float* b_d2 = (const float*)d_in[19];
    const int* edge_index = (const int*)d_in[20];
    const int* batch = (const int*)d_in[21];
    float* out = (float*)d_out;

    char* wp = (char*)d_ws;
    auto carve = [&](size_t bytes) {
        char* r = wp;
        wp += (bytes + 255) & ~(size_t)255;
        return r;
    };
    float* h = (float*)carve(sizeof(float) * (size_t)NN * 128);
    float* Ps = (float*)carve(sizeof(float) * (size_t)NN * 128);
    float* Pd = (float*)carve(sizeof(float) * (size_t)NN * 128);
    float* accm = (float*)carve(sizeof(float) * (size_t)NN * 128);
    float4* ea_s = (float4*)carve(sizeof(float4) * (size_t)EE);
    float* stats = (float*)carve(sizeof(float) * 4096);
    float* sum_hbc = stats + 1024;    // 1024
    float* cnt_node = stats + 2048;   // 8
    float* cnt_bc = stats + 2056;     // 8
    float* gterm = stats + 2304;      // 1024
    float* bfused = stats + 3328;     // 128
    float* part_h = (float*)carve(sizeof(float) * (size_t)BGRID * 1024);
    float* part_hbc = (float*)carve(sizeof(float) * (size_t)BGRID * 1024);
    float* partf = (float*)carve(sizeof(float) * (size_t)BGRID * 1024);
    int* deg = (int*)carve(sizeof(int) * NN);
    int* row_ptr = (int*)carve(sizeof(int) * (NN + 1));
    int* cursor = (int*)carve(sizeof(int) * NN);
    int* src_sorted = (int*)carve(sizeof(int) * EE);
    int* exbuf = (int*)carve(sizeof(int) * NN);
    int* blksum = (int*)carve(sizeof(int) * 256);
    float* Wf = (float*)carve(sizeof(float) * 16384);
    short* We2h = (short*)carve(sizeof(short) * 16384);
    short* We2l = (short*)carve(sizeof(short) * 16384);
    short* Wm1sh = (short*)carve(sizeof(short) * 16384);
    short* Wm1sl = (short*)carve(sizeof(short) * 16384);
    short* Wm1dh = (short*)carve(sizeof(short) * 16384);
    short* Wm1dl = (short*)carve(sizeof(short) * 16384);
    short* Wu1ah = (short*)carve(sizeof(short) * 16384);
    short* Wu1al = (short*)carve(sizeof(short) * 16384);
    short* Wfh = (short*)carve(sizeof(short) * 16384);
    short* Wfl = (short*)carve(sizeof(short) * 16384);
    short* Wu2h = (short*)carve(sizeof(short) * 16384);
    short* Wu2l = (short*)carve(sizeof(short) * 16384);
    short* Wd1h = (short*)carve(sizeof(short) * 16384);
    short* Wd1l = (short*)carve(sizeof(short) * 16384);

    const dim3 b256(256);
    const dim3 b512(512);
    const int gE256 = (EE + 255) / 256;

    // wfuse grid: 0..63 Wf, 64 bfuse+zero stats, 65..260 zero deg
    k_wfuse<<<261, b256, 0, stream>>>(W_m2, W_u1, b_m2, b_u1, Wf, bfused, stats, deg);
    k_pack_all<<<448, b256, 0, stream>>>(W_e2, W_m1, W_u1, Wf, W_u2, W_d1,
                                         We2h, We2l, Wm1sh, Wm1sl, Wm1dh, Wm1dl,
                                         Wu1ah, Wu1al, Wfh, Wfl, Wu2h, Wu2l, Wd1h, Wd1l);
    // CSR + per-graph counts (merged)
    k_count<<<gE256, b256, 0, stream>>>(edge_index, deg, batch, x_mask, cnt_node, cnt_bc);
    k_scan1<<<NBLK, b256, 0, stream>>>(deg, exbuf, blksum);
    k_scan2<<<1, b256, 0, stream>>>(blksum);
    k_scan3<<<NBLK, b256, 0, stream>>>(exbuf, blksum, row_ptr, cursor);
    k_scatter<<<gE256, b256, 0, stream>>>(edge_index, edge_attr, cursor, src_sorted, ea_s);
    // fused encoder: h + Ps + Pd + partial stats (512-thread blocks)
    k_genc<<<BGRID, b512, 0, stream>>>(x, x_mask, W_e1, b_e1, We2h, We2l, b_e2,
                                       Wm1sh, Wm1sl, Wm1dh, Wm1dl, b_m1, batch,
                                       h, Ps, Pd, part_h, part_hbc);

    const int EGRID = NN / 4 + GG;
    for (int rep = 0; rep < 3; ++rep) {
        if (rep == 0)
            k_edge_gterm<0><<<EGRID, b256, 0, stream>>>(Ps, Pd, row_ptr, src_sorted, ea_s, W_m1, accm,
                                                        part_h, part_hbc, sum_hbc, cnt_node, cnt_bc,
                                                        W_u1, gterm);
        else
            k_edge_gterm<1><<<EGRID, b256, 0, stream>>>(Ps, Pd, row_ptr, src_sorted, ea_s, W_m1, accm,
                                                        partf, nullptr, sum_hbc, cnt_node, cnt_bc,
                                                        W_u1, gterm);
        if (rep < 2) {
            k_fused3<0><<<BGRID, b512, 0, stream>>>(h, accm, Wu1ah, Wu1al, Wfh, Wfl, Wu2h, Wu2l,
                                                    Wm1sh, Wm1sl, Wm1dh, Wm1dl,
                                                    gterm, bfused, b_u2, b_m1, nullptr, nullptr,
                                                    nullptr, batch, h, Ps, Pd, partf, nullptr);
        } else {
            k_fused3<1><<<BGRID, b512, 0, stream>>>(h, accm, Wu1ah, Wu1al, Wfh, Wfl, Wu2h, Wu2l,
                                                    nullptr, nullptr, Wd1h, Wd1l,
                                                    gterm, bfused, b_u2, nullptr, b_d1, W_d2,
                                                    b_d2, batch, nullptr, nullptr, nullptr,
                                                    nullptr, out);
        }
    }
}